// Round 10
// baseline (838.323 us; speedup 1.0000x reference)
//
#include <hip/hip_runtime.h>
#include <hip/hip_bf16.h>
#include <math.h>

// ---------------------------------------------------------------------------
// WinFuncSelfAttention, Fourier-domain.
//   Tbf   bf16 [bs][c][1024p]
//   Wdft  bf16 [512 n=(m,q)][1024 p]
//   Xbf   bf16 [bs][m][256=2c+q]        (bs-major!)
//   Wqb   bf16 [m][768][256]
//   QKV   bf16 [nt:3][m][bs][256]       (split Q/K/V)
//   SAfb  bf16 ushort2 [bs][m][128]     (bs-major!)
//   OUTb  bf16 [m][bs][2c+q]
//   OUTt  bf16 [bs][c][2m+q]
//   Widf  bf16 [1024 p][512 n]
//   tmp   fp32 [bs][p][c]               (p-major rows of c!)
// KEY EMPIRICAL RULE (R4-R9): HBM write granularity ~= a 4KB page per
// WRITING BLOCK. Every destination's aligned 4KB pages must be written
// entirely by one block (within its lifetime) or WRITE_SIZE amplifies
// by ~4KB/bytes-per-page-per-block. All layouts above chosen so each
// block owns whole pages. (Reads are 64B-sector granular — unaffected.)
// ---------------------------------------------------------------------------

#define DEVI __device__ __forceinline__
typedef unsigned short u16;
typedef unsigned int u32;
typedef __attribute__((ext_vector_type(8))) short short8;
typedef __attribute__((ext_vector_type(4))) float f32x4;

DEVI u16 f2b(float f) {
  union { __hip_bfloat16 h; u16 u; } cv;
  cv.h = __float2bfloat16(f);
  return cv.u;
}
DEVI float b2f(u16 u) { return __uint_as_float(((u32)u) << 16); }

// ---------------- K0: bias = attn_mask + log-CPB MLP -----------------------
__global__ __launch_bounds__(256) void k_bias(
    const float* __restrict__ w1, const float* __restrict__ b1,
    const float* __restrict__ w2, const float* __restrict__ amask,
    float* __restrict__ biasb) {
  __shared__ float w1s[1024];
  __shared__ float b1s[512];
  __shared__ float w2s[4096];
  int t = threadIdx.x;
  for (int k = t; k < 1024; k += 256) w1s[k] = w1[k];
  for (int k = t; k < 512; k += 256) b1s[k] = b1[k];
  for (int k = t; k < 4096; k += 256) w2s[k] = w2[k];
  __syncthreads();
  int i = t >> 4, j = t & 15;
  float r0 = (float)((i >> 2) - (j >> 2));
  float r1 = (float)((i & 3) - (j & 3));
  const float sc = 8.0f / 3.0f;  // 8 / log2(8)
  float f0 = (r0 == 0.f) ? 0.f : copysignf(log2f(1.f + fabsf(r0)) * sc, r0);
  float f1 = (r1 == 0.f) ? 0.f : copysignf(log2f(1.f + fabsf(r1)) * sc, r1);
  float o[8];
#pragma unroll
  for (int h = 0; h < 8; h++) o[h] = 0.f;
  for (int k = 0; k < 512; k++) {
    float hd = f0 * w1s[k] + f1 * w1s[512 + k] + b1s[k];
    hd = fmaxf(hd, 0.f);
#pragma unroll
    for (int h = 0; h < 8; h++) o[h] += hd * w2s[k * 8 + h];
  }
  for (int w = 0; w < 4; w++)
#pragma unroll
    for (int h = 0; h < 8; h++) {
      int idx = ((w * 8 + h) * 16 + i) * 16 + j;
      biasb[idx] = amask[idx] + o[h];
    }
}

// ---------------- T: weight transpose wr/wi[c][o][m] -> dst[m][c][o] bf16 --
__global__ __launch_bounds__(256) void k_transpose_wb(
    const float* __restrict__ wr, const float* __restrict__ wi,
    ushort2* __restrict__ dst, int N) {
  __shared__ ushort2 ld[256][17];
  int t = threadIdx.x;
  int ob = blockIdx.x * 16;
  int cb = blockIdx.y * 8;
  for (int cc = 0; cc < 8; cc++) {
    int c = cb + cc;
    for (int oo = 0; oo < 16; oo++) {
      size_t si = ((size_t)c * N + ob + oo) * 256 + t;
      ushort2 u;
      u.x = f2b(wr[si]);
      u.y = f2b(wi[si]);
      ld[t][oo] = u;
    }
    __syncthreads();
    {
      int oo = t & 15, tq = t >> 4;
#pragma unroll
      for (int mr = 0; mr < 16; mr++) {
        int m = mr * 16 + tq;
        dst[((size_t)m * 128 + c) * N + ob + oo] = ld[m][oo];
      }
    }
    __syncthreads();
  }
}

// ---------------- B-build: Ws1[m][c][o] bf16 -> Bt[m][n=2o+p][k=2c+q] ------
template <int N>
__global__ __launch_bounds__(256) void k_build_b(
    const ushort2* __restrict__ Ws1, u16* __restrict__ Bt) {
  __shared__ ushort2 tile[128][65];
  int t = threadIdx.x;
  int ob = blockIdx.x;  // 64-o chunk
  int m = blockIdx.y;
  {
    int c4 = t >> 6, o = t & 63;
    for (int cc = 0; cc < 32; cc++) {
      int c = cc * 4 + c4;
      tile[c][o] = Ws1[((size_t)m * 128 + c) * N + ob * 64 + o];
    }
  }
  __syncthreads();
  int l = t & 63, w2 = t >> 6;
  for (int rr = 0; rr < 32; rr++) {
    int r = w2 * 32 + rr;  // local n row
    int ol = r >> 1, p = r & 1;
    size_t rowoff = ((size_t)m * (2 * N) + (size_t)ob * 128 + r) * 256;
#pragma unroll
    for (int ch = 0; ch < 2; ch++) {
      int c = ch * 64 + l;
      ushort2 wv = tile[c][ol];
      ushort2 u;
      u.x = p ? wv.y : wv.x;
      u.y = p ? wv.x : (u16)(wv.y ^ 0x8000);  // bf16 negate = sign flip
      *(ushort2*)(Bt + rowoff + 2 * c) = u;
    }
  }
}

// ---------------- W-dft build: n=(m,q) rows of cos / -sin ------------------
__global__ __launch_bounds__(256) void k_build_wdft(u16* __restrict__ Wdft) {
  int n = blockIdx.x;  // 0..511
  int m = n >> 1, q = n & 1;
  int kx = m >> 4, ky = m & 15;
  int t = threadIdx.x;
#pragma unroll
  for (int i = 0; i < 4; i++) {
    int p = i * 256 + t;
    int u = p >> 5, v = p & 31;
    int ph = (kx * u + ky * v) & 31;
    float th = 6.283185307179586f * (float)ph / 32.f;
    float sv, cv;
    sincosf(th, &sv, &cv);
    Wdft[(size_t)n * 1024 + p] = f2b(q ? -sv : cv);
  }
}

// ---------------- W-idft build: Widf[p=1024][n=512], c2r + 1/1024 folded ---
__global__ __launch_bounds__(256) void k_build_widft(u16* __restrict__ Widf) {
  int p = blockIdx.x;  // 0..1023
  int x = p >> 5, y = p & 31;
  for (int n = threadIdx.x; n < 512; n += 256) {
    int m = n >> 1, q = n & 1;
    int kx = m >> 4, ky = m & 15;
    int ph = (kx * x + ky * y) & 31;
    float th = 6.283185307179586f * (float)ph / 32.f;
    float sv, cv;
    sincosf(th, &sv, &cv);
    float cky = (ky == 0) ? (1.f / 1024.f) : (2.f / 1024.f);
    Widf[(size_t)p * 512 + n] = f2b(q ? -sv * cky : cv * cky);
  }
}

// ---------------- gather: shifted spatial tiles -> Tbf[bs][c][1024] bf16 ---
__global__ __launch_bounds__(256) void k_gather(
    const float* __restrict__ seq, u16* __restrict__ Tbf) {
  int t = threadIdx.x;
  int cq = blockIdx.x;  // 0..3
  int bs = blockIdx.y;
  int b = bs >> 4, s = bs & 15;
  int qx = s >> 2, qy = s & 3;
  int u = t >> 3, vb = (t & 7) * 4;
  int uu = u + 16;
  int u2 = uu & 31;
  int qx2 = (qx + (uu >> 5)) & 3;
  int vv = vb + 16;
  int v2 = vv & 31;
  int qy2 = (qy + (vv >> 5)) & 3;
  int s2 = qx2 * 4 + qy2;
  size_t srcbase = (((size_t)(b * 16 + s2) * 128) << 10) + u2 * 32 + v2;
  size_t dstbase = (((size_t)bs * 128) << 10) + u * 32 + vb;
  for (int cc = 0; cc < 32; cc++) {
    size_t coff = (size_t)(cq * 32 + cc) << 10;
    float4 v = *(const float4*)(seq + srcbase + coff);
    ushort4 o;
    o.x = f2b(v.x);
    o.y = f2b(v.y);
    o.z = f2b(v.z);
    o.w = f2b(v.w);
    *(ushort4*)(Tbf + dstbase + coff) = o;
  }
}

// ---------------- dftm: per-bs GEMM Wdft[512][1024] @ Tbf[bs][128][1024]^T -
// Output Xbf[bs][m][256]: block writes 64KB contiguous (page-exclusive).
__global__ __launch_bounds__(512) void k_dftm(
    const u16* __restrict__ Wdft, const u16* __restrict__ Tbf,
    u16* __restrict__ Xbf) {
  __shared__ char lds[49152];
  char* As = lds;          // 256 rows x 64k bf16, swizzled
  char* Bs = lds + 32768;  // 128 rows x 64k
  u16* st = (u16*)lds;     // epilogue stage: 64 rows x 264 u16
  int t = threadIdx.x;
  int mt = blockIdx.x, bs = blockIdx.y;
  int l = t & 63, w = t >> 6;
  int wm = w >> 1, wn = w & 1;  // 4x2 wave grid, 64x64 out each
  f32x4 acc[4][4];
#pragma unroll
  for (int a_ = 0; a_ < 4; a_++)
#pragma unroll
    for (int b_ = 0; b_ < 4; b_++) acc[a_][b_] = (f32x4){0.f, 0.f, 0.f, 0.f};
  const u16* Ab = Wdft + (size_t)mt * 256 * 1024;
  const u16* Bb = Tbf + (size_t)bs * 128 * 1024;
  int srow = t >> 3, ss = t & 7;  // srow 0..63
  uint4 ra[4], rb[2];
#pragma unroll
  for (int i = 0; i < 4; i++)
    ra[i] = *(const uint4*)(Ab + (size_t)(i * 64 + srow) * 1024 + ss * 8);
#pragma unroll
  for (int i = 0; i < 2; i++)
    rb[i] = *(const uint4*)(Bb + (size_t)(i * 64 + srow) * 1024 + ss * 8);
  for (int kt = 0; kt < 16; kt++) {
    if (kt) __syncthreads();
#pragma unroll
    for (int i = 0; i < 4; i++) {
      int row = i * 64 + srow;
      *(uint4*)(As + row * 128 + ((ss ^ (row & 7)) << 4)) = ra[i];
    }
#pragma unroll
    for (int i = 0; i < 2; i++) {
      int row = i * 64 + srow;
      *(uint4*)(Bs + row * 128 + ((ss ^ (row & 7)) << 4)) = rb[i];
    }
    if (kt < 15) {
#pragma unroll
      for (int i = 0; i < 4; i++)
        ra[i] = *(const uint4*)(Ab + (size_t)(i * 64 + srow) * 1024 +
                                (kt + 1) * 64 + ss * 8);
#pragma unroll
      for (int i = 0; i < 2; i++)
        rb[i] = *(const uint4*)(Bb + (size_t)(i * 64 + srow) * 1024 +
                                (kt + 1) * 64 + ss * 8);
    }
    __syncthreads();
#pragma unroll
    for (int kk = 0; kk < 2; kk++) {
      short8 af[4], bg[4];
#pragma unroll
      for (int fm = 0; fm < 4; fm++) {
        int row = wm * 64 + fm * 16 + (l & 15);
        int chunk = kk * 4 + (l >> 4);
        af[fm] = *(const short8*)(As + row * 128 + ((chunk ^ (row & 7)) << 4));
      }
#pragma unroll
      for (int fn = 0; fn < 4; fn++) {
        int row = wn * 64 + fn * 16 + (l & 15);
        int chunk = kk * 4 + (l >> 4);
        bg[fn] = *(const short8*)(Bs + row * 128 + ((chunk ^ (row & 7)) << 4));
      }
#pragma unroll
      for (int fm = 0; fm < 4; fm++)
#pragma unroll
        for (int fn = 0; fn < 4; fn++)
          acc[fm][fn] = __builtin_amdgcn_mfma_f32_16x16x32_bf16(
              af[fm], bg[fn], acc[fm][fn], 0, 0, 0);
    }
  }
  // epilogue: 2 passes of 64 m-rows; Xbf[bs][m][256] contiguous stores.
  int cr = (l >> 4) * 4, ccol = l & 15;
  for (int pass = 0; pass < 2; pass++) {
    __syncthreads();
    if ((wm >> 1) == pass) {
#pragma unroll
      for (int fm = 0; fm < 4; fm++) {
#pragma unroll
        for (int fn = 0; fn < 4; fn++) {
          int c = wn * 64 + fn * 16 + ccol;
#pragma unroll
          for (int rp = 0; rp < 4; rp += 2) {
            int rloc = (wm & 1) * 32 + fm * 8 + ((cr + rp) >> 1);
            ushort2 ub;
            ub.x = f2b(acc[fm][fn][rp]);
            ub.y = f2b(acc[fm][fn][rp + 1]);
            *(ushort2*)(st + rloc * 264 + 2 * c) = ub;
          }
        }
      }
    }
    __syncthreads();
#pragma unroll
    for (int it = 0; it < 4; it++) {
      int idx = it * 512 + t;  // 0..2047
      int row = idx >> 5;      // m_local within pass
      int ch = idx & 31;
      uint4 v = *(const uint4*)(st + row * 264 + ch * 8);
      int m = mt * 128 + pass * 64 + row;
      *(uint4*)(Xbf + ((size_t)bs * 256 + m) * 256 + ch * 8) = v;
    }
  }
}

// ---------------- Gram via MFMA: G[b,h] = X X^T over (4ch x 1024p) ---------
__global__ __launch_bounds__(64) void k_gram_mfma(
    const u16* __restrict__ Tbf, float* __restrict__ Gpart) {
  int dc = blockIdx.x;  // 0..3 channel quarter
  int bh = blockIdx.y;  // 0..127
  int b = bh >> 3, h = bh & 7;
  int l = threadIdx.x;  // 0..63
  f32x4 a0 = (f32x4){0.f, 0.f, 0.f, 0.f};
  f32x4 a1 = (f32x4){0.f, 0.f, 0.f, 0.f};
  const u16* base =
      Tbf + ((size_t)(b * 16 + (l & 15)) * 128 + h * 16 + dc * 4) * 1024;
  int ko = (l >> 4) * 8;
  for (int kk = 0; kk < 128; kk += 2) {
    short8 f0 = *(const short8*)(base + kk * 32 + ko);
    short8 f1 = *(const short8*)(base + kk * 32 + 32 + ko);
    a0 = __builtin_amdgcn_mfma_f32_16x16x32_bf16(f0, f0, a0, 0, 0, 0);
    a1 = __builtin_amdgcn_mfma_f32_16x16x32_bf16(f1, f1, a1, 0, 0, 0);
  }
  float* dst = Gpart + ((size_t)(dc * 16 + b) * 8 + h) * 256;
#pragma unroll
  for (int r = 0; r < 4; r++)
    dst[((l >> 4) * 4 + r) * 16 + (l & 15)] = a0[r] + a1[r];
}

// ---------------- MFMA per-mode GEMM: C = A (bs-major) @ B[m]' -------------
// A = [bs][m][256] bf16; out [nt][m][bs][256] (block-exclusive 128KB).
template <int NP>
__global__ __launch_bounds__(512) void k_mixm(
    const u16* __restrict__ A, const u16* __restrict__ Bm,
    u16* __restrict__ Cb) {
  __shared__ char lds[65536];
  char* As = lds;          // 256 rows (bs) x 64 k bf16, swizzled
  char* Bs = lds + 32768;  // 256 rows (n)  x 64 k
  u16* st = (u16*)lds;     // epilogue stage: 64 rows x 264 u16 (pad 8)
  int t = threadIdx.x;
  const int gx = NP / 256;
  int orig = blockIdx.y * gx + blockIdx.x;
  const int tot = gx * 256;
  int lid = (orig & 7) * (tot >> 3) + (orig >> 3);  // XCD-chunked (tot%8==0)
  int nt = lid % gx;
  int m = lid / gx;
  int l = t & 63, w = t >> 6;
  int wm = w >> 1, wn = w & 1;  // wave tile: 64 bs x 128 n
  f32x4 acc[4][8];
#pragma unroll
  for (int a_ = 0; a_ < 4; a_++)
#pragma unroll
    for (int b_ = 0; b_ < 8; b_++) acc[a_][b_] = (f32x4){0.f, 0.f, 0.f, 0.f};
  const u16* Bb = Bm + ((size_t)m * NP + nt * 256) * 256;
  int srow = t >> 3, ss = t & 7;  // srow 0..63, ss = k-chunk
  uint4 ra[4], rb[4];
#pragma unroll
  for (int i = 0; i < 4; i++) {
    int row = i * 64 + srow;
    ra[i] = *(const uint4*)(A + ((size_t)row * 256 + m) * 256 + ss * 8);
    rb[i] = *(const uint4*)(Bb + (size_t)row * 256 + ss * 8);
  }
  for (int kt = 0; kt < 4; kt++) {
    if (kt) __syncthreads();
#pragma unroll
    for (int i = 0; i < 4; i++) {
      int row = i * 64 + srow;
      int sw = ((ss ^ (row & 7)) << 4);
      *(uint4*)(As + row * 128 + sw) = ra[i];
      *(uint4*)(Bs + row * 128 + sw) = rb[i];
    }
    if (kt < 3) {
#pragma unroll
      for (int i = 0; i < 4; i++) {
        int row = i * 64 + srow;
        ra[i] = *(const uint4*)(A + ((size_t)row * 256 + m) * 256 +
                                (kt + 1) * 64 + ss * 8);
        rb[i] =
            *(const uint4*)(Bb + (size_t)row * 256 + (kt + 1) * 64 + ss * 8);
      }
    }
    __syncthreads();
#pragma unroll
    for (int kk = 0; kk < 2; kk++) {
      short8 af[4], bg[8];
#pragma unroll
      for (int fm = 0; fm < 4; fm++) {
        int row = wm * 64 + fm * 16 + (l & 15);
        int chunk = kk * 4 + (l >> 4);
        af[fm] = *(const short8*)(As + row * 128 + ((chunk ^ (row & 7)) << 4));
      }
#pragma unroll
      for (int fn = 0; fn < 8; fn++) {
        int row = wn * 128 + fn * 16 + (l & 15);
        int chunk = kk * 4 + (l >> 4);
        bg[fn] = *(const short8*)(Bs + row * 128 + ((chunk ^ (row & 7)) << 4));
      }
#pragma unroll
      for (int fm = 0; fm < 4; fm++)
#pragma unroll
        for (int fn = 0; fn < 8; fn++)
          acc[fm][fn] = __builtin_amdgcn_mfma_f32_16x16x32_bf16(
              bg[fn], af[fm], acc[fm][fn], 0, 0, 0);  // C^T fragments
    }
  }
  // epilogue: per fm, stage 64 bs x 256 n bf16 in LDS, store 512B rows.
#pragma unroll
  for (int fm = 0; fm < 4; fm++) {
    __syncthreads();
    int rloc = wm * 16 + (l & 15);
#pragma unroll
    for (int fn = 0; fn < 8; fn++) {
      int col = wn * 128 + fn * 16 + (l >> 4) * 4;
      ushort4 u;
      u.x = f2b(acc[fm][fn][0]);
      u.y = f2b(acc[fm][fn][1]);
      u.z = f2b(acc[fm][fn][2]);
      u.w = f2b(acc[fm][fn][3]);
      *(ushort4*)(st + rloc * 264 + col) = u;
    }
    __syncthreads();
#pragma unroll
    for (int it = 0; it < 4; it++) {
      int idx = it * 512 + t;  // 0..2047
      int row = idx >> 5;      // 0..63
      int ch = idx & 31;       // 16B chunk within 512B row
      uint4 v = *(const uint4*)(st + row * 264 + ch * 8);
      int bs = (row >> 4) * 64 + fm * 16 + (row & 15);
      *(uint4*)(Cb + ((size_t)nt * 65536 + (size_t)m * 256 + bs) * 256 +
                ch * 8) = v;
    }
  }
}

// ---------------- transpose: OUTb[m][bs][2c+q] -> OUTt[bs][c][2m+q] --------
__global__ __launch_bounds__(256) void k_transp_out(
    const ushort2* __restrict__ OUTb2, ushort2* __restrict__ OUTt2) {
  __shared__ ushort2 ld[128][129];
  int t = threadIdx.x;
  int bs = blockIdx.x;
  for (int mh = 0; mh < 2; mh++) {
    if (mh) __syncthreads();
    {
      int cidx = t & 127;
      int rb = t >> 7;
      for (int pass = 0; pass < 64; pass++) {
        int r = pass * 2 + rb;
        ld[r][cidx] = OUTb2[((size_t)(mh * 128 + r) * 256 + bs) * 128 + cidx];
      }
    }
    __syncthreads();
    {
      int ml = t & 127;
      int cb = t >> 7;
      for (int pass = 0; pass < 64; pass++) {
        int c = pass * 2 + cb;
        OUTt2[((size_t)bs * 128 + c) * 256 + mh * 128 + ml] = ld[ml][c];
      }
    }
  }
}

// ---------------- irfftm: tmp[bs][p][c] = Widf @ OUTt (block-owned pages) --
__global__ __launch_bounds__(512) void k_irfftm(
    const u16* __restrict__ Widf, const u16* __restrict__ OUTt,
    float* __restrict__ tmp) {
  __shared__ char lds[65536];
  char* As = lds;            // 256 p-rows x 64k bf16, swizzled
  char* Bs = lds + 32768;    // 128 c-rows x 64k
  float* stg = (float*)lds;  // epilogue stage [128 p][128 c] fp32, swizzled
  int t = threadIdx.x;
  int ph = blockIdx.x, bs = blockIdx.y;
  int l = t & 63, w = t >> 6;
  int wm = w >> 1, wn = w & 1;  // 4(p) x 2(c) waves, 64x64 out each
  f32x4 acc[4][4];
#pragma unroll
  for (int a_ = 0; a_ < 4; a_++)
#pragma unroll
    for (int b_ = 0; b_ < 4; b_++) acc[a_][b_] = (f32x4){0.f, 0.f, 0.f, 0.f};
  const u16* Ab = Widf + (size_t)ph * 256 * 512;
  const u16* Bb = OUTt + (size_t)bs * 128 * 512;
  int srow = t >> 3, ss = t & 7;
  uint4 ra[4], rb[2];
#pragma unroll
  for (int i = 0; i < 4; i++)
    ra[i] = *(const uint4*)(Ab + (size_t)(i * 64 + srow) * 512 + ss * 8);
#pragma unroll
  for (int i = 0; i < 2; i++)
    rb[i] = *(const uint4*)(Bb + (size_t)(i * 64 + srow) * 512 + ss * 8);
  for (int kt = 0; kt < 8; kt++) {
    if (kt) __syncthreads();
#pragma unroll
    for (int i = 0; i < 4; i++) {
      int row = i * 64 + srow;
      *(uint4*)(As + row * 128 + ((ss ^ (row & 7)) << 4)) = ra[i];
    }
#pragma unroll
    for (int i = 0; i < 2; i++) {
      int row = i * 64 + srow;
      *(uint4*)(Bs + row * 128 + ((ss ^ (row & 7)) << 4)) = rb[i];
    }
    if (kt < 7) {
#pragma unroll
      for (int i = 0; i < 4; i++)
        ra[i] = *(const uint4*)(Ab + (size_t)(i * 64 + srow) * 512 +
                                (kt + 1) * 64 + ss * 8);
#pragma unroll
      for (int i = 0; i < 2; i++)
        rb[i] = *(const uint4*)(Bb + (size_t)(i * 64 + srow) * 512 +
                                (kt + 1) * 64 + ss * 8);
    }
    __syncthreads();
#pragma unroll
    for (int kk = 0; kk < 2; kk++) {
      short8 wf[4], bg[4];
#pragma unroll
      for (int fm = 0; fm < 4; fm++) {
        int row = wm * 64 + fm * 16 + (l & 15);
        int chunk = kk * 4 + (l >> 4);
        wf[fm] = *(const short8*)(As + row * 128 + ((chunk ^ (row & 7)) << 4));
      }
#pragma unroll
      for (int fn = 0; fn < 4; fn++) {
        int row = wn * 64 + fn * 16 + (l & 15);
        int chunk = kk * 4 + (l >> 4);
        bg[fn] = *(const short8*)(Bs + row * 128 + ((chunk ^ (row & 7)) << 4));
      }
#pragma unroll
      for (int fm = 0; fm < 4; fm++)
#pragma unroll
        for (int fn = 0; fn < 4; fn++)
          acc[fm][fn] = __builtin_amdgcn_mfma_f32_16x16x32_bf16(
              wf[fm], bg[fn], acc[fm][fn], 0, 0, 0);
    }
  }
  // epilogue: lane holds p = wm*64+fm*16+(l>>4)*4+r, c = wn*64+fn*16+(l&15).
  // two passes of 128 p-rows; stage [p_local][c] fp32, chunk-XOR swizzled.
  for (int pass = 0; pass < 2; pass++) {
    __syncthreads();
    if ((wm >> 1) == pass) {
#pragma unroll
      for (int fm = 0; fm < 4; fm++) {
#pragma unroll
        for (int fn = 0; fn < 4; fn++) {
          int c = wn * 64 + fn * 16 + (l & 15);
#pragma unroll
          for (int r = 0; r < 4; r++) {
            int pl = (wm & 1) * 64 + fm * 16 + (l >> 4) * 4 + r;
            stg[pl * 128 + (((c >> 2) ^ (pl & 7)) << 2) + (c & 3)] =
                acc[fm][fn][r];
          }
        }
      }
    }
    __syncthreads();
#pragma unroll
    for (int it = 0; it < 8; it++) {
      int ci = it * 512 + t;  // 0..4095 float4-chunks
      int prow = ci >> 5, ch = ci & 31;
      float4 v = *(const float4*)(stg + prow * 128 + ((ch ^ (prow & 7)) << 2));
      int p = ph * 256 + pass * 128 + prow;
      *(float4*)(tmp + ((size_t)bs * 1024 + p) * 128 + ch * 4) = v;
    }
  }
}

// ---------------- unshift: out[bs2][c][u2][v2] = tmp[bs_src][x*32+y][c] ----
// LDS transpose per u2-row: reads 512B p-rows, writes full (bs2,c) pages.
__global__ __launch_bounds__(256) void k_unshift(
    const float* __restrict__ tmp, float* __restrict__ out) {
  __shared__ float ld[2][32][132];
  int t = threadIdx.x;
  int bs2 = blockIdx.x;
  int b = bs2 >> 4, s2 = bs2 & 15;
  int qx2 = s2 >> 2, qy2 = s2 & 3;
  for (int u2 = 0; u2 < 32; u2++) {
    int cu = u2 & 1;
    int x = (u2 < 16) ? u2 + 16 : u2 - 16;
    int qx = (u2 < 16) ? (qx2 + 3) & 3 : qx2;
    {
      int r = t >> 3;  // v2 row 0..31
      int y = (r < 16) ? r + 16 : r - 16;
      int qy = (r < 16) ? (qy2 + 3) & 3 : qy2;
      int bs_src = b * 16 + qx * 4 + qy;
      const float* src = tmp + ((size_t)bs_src * 1024 + x * 32 + y) * 128;
#pragma unroll
      for (int k = 0; k < 4; k++) {
        int c4 = (t & 7) + 8 * k;
        float4 v = *(const float4*)(src + c4 * 4);
        ld[cu][r][c4 * 4 + 0] = v.x;
        ld[cu][r][c4 * 4 + 1] = v.y;
        ld[cu][r][c4 * 4 + 2] = v.z;
        ld[cu][r][c4 * 4 + 3] = v.w;
      }
    }
    __syncthreads();
    {
      int c = t >> 1, vh = (t & 1) * 16;
      float* dst = out + (((size_t)bs2 * 128 + c) << 10) + u2 * 32 + vh;
#pragma unroll
      for (int k = 0; k < 4; k++) {
        float4 v = make_float4(ld[cu][vh + k * 4 + 0][c],
                               ld[cu][vh + k * 4 + 1][c],
                               ld[cu][vh + k * 4 + 2][c],
                               ld[cu][vh + k * 4 + 3][c]);
        *(float4*)(dst + k * 4) = v;
      }
    }
  }
}

// ---------------- K3: score partials over low modes ------------------------
__global__ __launch_bounds__(256) void k_scores(
    const ushort2* __restrict__ Xb2, const ushort2* __restrict__ Qb2,
    const ushort2* __restrict__ Kb2, float* __restrict__ Spart) {
  __shared__ float2 Xs[16][17], Qs[16][17], Ks[16][17];
  int t = threadIdx.x;
  int mc = blockIdx.x;
  int bh = blockIdx.y;
  int b = bh >> 3, h = bh & 7;
  int i = t >> 4, j = t & 15;
  int bs = b * 16 + i;
  int d = j;
  int m0 = mc * 32;
  size_t xoff = ((size_t)bs * 256 + m0) * 128 + h * 16 + d;
  size_t qoff = ((size_t)m0 * 256 + bs) * 128 + h * 16 + d;
  ushort2 ux = Xb2[xoff];
  ushort2 uq = Qb2[qoff];
  ushort2 uk = Kb2[qoff];
  float acc = 0.f;
  for (int mm = 0; mm < 32; mm++) {
    int m = m0 + mm;
    Xs[i][d] = make_float2(b2f(ux.x), b2f(ux.y));
    Qs[i][d] = make_float2(b2f(uq.x), b2f(uq.y));
    Ks[i][d] = make_float2(b2f(uk.x), b2f(uk.y));
    __syncthreads();
    if (mm < 31) {
      ux = Xb2[xoff + (size_t)(mm + 1) * 128];
      uq = Qb2[qoff + (size_t)(mm + 1) * 32768];
      uk = Kb2[qoff + (size_t)(mm + 1) * 32768];
    }
    int ky = m & 15, kx = m >> 4;
    if (ky > 0) {
#pragma unroll
      for (int dd = 0; dd < 16; dd++) {
        float2 Xi = Xs[i][dd], Qi = Qs[i][dd], Xj = Xs[j][dd], Kj = Ks[j][dd];
        float qr = Xi.x + Qi.x, qi = Xi.y + Qi.y;
        float kr = Xj.x + Kj.x, ki = Xj.y + Kj.y;
        acc += 2.f * (qr * kr + qi * ki - (Xi.x * Xj.x + Xi.y * Xj.y));
      }
    } else {
#pragma unroll
      for (int dd = 0; dd < 16; dd++) {
        float2 Xi = Xs[i][dd], Qi = Qs[i][dd], Xj = Xs[j][dd], Kj = Ks[j][dd];
        float cr = Xi.x * Kj.x + Xi.y * Kj.y + Qi.x * Xj.x + Qi.y * Xj.y;
        float qk =
            (kx == 0) ? (Qi.x * Kj.x) : 0.5f * (Qi.x * Kj.x + Qi.y * Kj.y);
        acc += cr + qk;
      }
    }
    __syncthreads();
  }
  Spart[((size_t)mc * 128 + bh) * 256 + t] = acc;
}

// ---------------- K3b: assemble scores, bias, softmax ----------------------
__global__ __launch_bounds__(256) void k_softmax(
    const float* __restrict__ Spart, const float* __restrict__ Gpart,
    const float* __restrict__ biasb, float* __restrict__ attn) {
  int t = threadIdx.x;
  int bh = blockIdx.x;
  int b = bh >> 3, h = bh & 7;
  int i = t >> 4, j = t & 15;
  float acc = 0.f;
#pragma unroll
  for (int mc = 0; mc < 8; mc++)
    acc += Spart[((size_t)mc * 128 + bh) * 256 + t];
  float G = 0.f;
#pragma unroll
  for (int dc = 0; dc < 4; dc++)
    G += Gpart[((size_t)(dc * 16 + b) * 8 + h) * 256 + t];
  float score = G * (1.f / 4096.f) + acc * (1.f / 4194304.f) +
                biasb[(((b & 3) * 8 + h) * 16 + i) * 16 + j];
  float mx = score;
#pragma unroll
  for (int o = 8; o >= 1; o >>= 1) mx = fmaxf(mx, __shfl_xor(mx, o, 16));
  float e = expf(score - mx);
  float sm = e;
#pragma unroll
  for (int o = 8; o >= 1; o >>= 1) sm += __shfl_xor(sm, o, 16);
  attn[(size_t)bh * 256 + t] = e / sm;
}

// ---------------- K4: SAf[bs][m][c] = attn @ (X + Vm~)  (bf16 out) ---------
__global__ __launch_bounds__(256) void k_sav(
    const ushort2* __restrict__ Xb2, const ushort2* __restrict__ Vb2,
    const float* __restrict__ attn, ushort2* __restrict__ SAfb) {
  __shared__ float at[8][16][17];
  __shared__ float2 vt[16][130];
  int t = threadIdx.x;
  int mc = blockIdx.x;
  int b = blockIdx.y;
  {
    int h = t >> 5, ii = (t >> 1) & 15, jb = (t & 1) * 8;
#pragma unroll
    for (int k = 0; k < 8; k++)
      at[h][ii][jb + k] = attn[((size_t)(b * 8 + h) * 16 + ii) * 16 + jb + k];
  }
  __syncthreads();
  int i = t >> 4, cg = t & 15;
  for (int mm = 0; mm < 16; mm++) {
    int m = mc * 16 + mm;
    int ky = m & 15, kx = m >> 4;
    {
      int jj = t >> 4;
      size_t vrow = ((size_t)m * 256 + b * 16 + jj) * 128;
      size_t xrow = ((size_t)(b * 16 + jj) * 256 + m) * 128;
#pragma unroll
      for (int u = 0; u < 8; u++) {
        int c = cg + u * 16;
        ushort2 uv = Vb2[vrow + c];
        float2 vm = make_float2(b2f(uv.x), b2f(uv.y));
        ushort2 uxv = Xb2[xrow + c];
        float2 xv = make_float2(b2f(uxv.x), b2f(uxv.y));
        float2 vh;
        if (ky == 0) {
          if (kx == 0)
            vh = make_float2(xv.x + vm.x, xv.y);
          else
            vh = make_float2(xv.x + 0.5f * vm.x, xv.y + 0.5f * vm.y);
        } else
          vh = make_float2(xv.x + vm.x, xv.y + vm.y);
        vt[jj][c] = vh;
      }
    }
    __syncthreads();
    float2 o8[8];
#pragma unroll
    for (int u = 0; u < 8; u++) o8[u] = make_float2(0.f, 0.f);
#pragma unroll
    for (int jj = 0; jj < 16; jj++) {
#pragma unroll
      for (int u = 0; u < 8; u++) {
        float av = at[u][i][jj];
        float2 v = vt[jj][cg + u * 16];
        o8[u].x += av * v.x;
        o8[u].y += av * v.y;
      }
    }
    size_t orow = ((size_t)(b * 16 + i) * 256 + m) * 128;  // [bs][m][128]
#pragma unroll
    for (int u = 0; u < 8; u++) {
      ushort2 ub;
      ub.x = f2b(o8[u].x);
      ub.y = f2b(o8[u].y);
      SAfb[orow + cg + u * 16] = ub;
    }
    __syncthreads();
  }
}

// ---------------------------------------------------------------------------
extern "C" void kernel_launch(void* const* d_in, const int* in_sizes, int n_in,
                              void* d_out, int out_size, void* d_ws,
                              size_t ws_size, hipStream_t stream) {
  (void)in_sizes;
  (void)n_in;
  const float* seq = (const float*)d_in[0];
  const float* qwr = (const float*)d_in[1];
  const float* qwi = (const float*)d_in[2];
  const float* owr = (const float*)d_in[3];
  const float* owi = (const float*)d_in[4];
  const float* cw1 = (const float*)d_in[5];
  const float* cb1 = (const float*)d_in[6];
  const float* cw2 = (const float*)d_in[7];
  const float* amask = (const float*)d_in[8];
  float* out = (float*)d_out;
  char* ws = (char*)d_ws;

  const size_t R = 100663296;  // 96 MiB region
  // R1: Wq_s1b (50.3MB) -> Tbf (67MB) + Xbf (33.5MB); Wob aliases Tbf
  ushort2* Wq_s1b = (ushort2*)ws;
  u16* Tbf = (u16*)ws;
  u16* Xbf = (u16*)(ws + 67108864);  // [bs][m][256]
  ushort2* Xb2 = (ushort2*)Xbf;
  u16* Wob = (u16*)ws;
  // R2: QKV [3][m][bs][256] (100.6MB) -> after sav: OUTb + OUTt
  u16* QKV = (u16*)(ws + R);
  ushort2* Qb2 = (ushort2*)QKV;
  ushort2* Kb2 = Qb2 + 8388608;
  ushort2* Vb2 = Qb2 + 16777216;
  u16* OUTb = (u16*)(ws + R);
  u16* OUTt = (u16*)(ws + R + 33554432);
  // tmp fp32 [bs][p][c] = 128 MiB at [160 MiB, 288 MiB)
  float* tmpb = (float*)(ws + R + 2 * 33554432);
  // R3: Wqb (100.6MB) -> SAfb (33.5MB) after mix1
  u16* Wqb = (u16*)(ws + 2 * R);
  ushort2* SAfb = (ushort2*)(ws + 2 * R);
  // R4: Wo_s1b bf16 (16.8MB)
  ushort2* Wo_s1b = (ushort2*)(ws + 3 * R);
  char* sm = ws + 3 * R + 16777216 + 67108864;
  u16* Wdft = (u16*)sm;                   // 1,048,576
  float* Gpart = (float*)(sm + 1048576);  // 524,288
  float* biasb = (float*)(sm + 1572864);  // 32,768
  float* attn = (float*)(sm + 1605632);   // 131,072
  float* Spart = (float*)(sm + 1736704);  // 1,048,576
  u16* Widf = (u16*)(sm + 2785280);       // 1,048,576
  size_t need = 3 * R + 16777216 + 67108864 + 2785280 + 1048576;

  if (ws_size < need) {
    hipMemsetAsync(d_out, 0, (size_t)out_size * 4, stream);
    return;
  }

  dim3 blk(256);
  k_transpose_wb<<<dim3(24, 16), blk, 0, stream>>>(qwr, qwi, Wq_s1b, 384);
  k_build_b<384><<<dim3(6, 256), blk, 0, stream>>>(Wq_s1b, Wqb);
  k_transpose_wb<<<dim3(8, 16), blk, 0, stream>>>(owr, owi, Wo_s1b, 128);
  k_bias<<<dim3(1), blk, 0, stream>>>(cw1, cb1, cw2, amask, biasb);
  k_build_wdft<<<dim3(512), blk, 0, stream>>>(Wdft);
  k_build_widft<<<dim3(1024), blk, 0, stream>>>(Widf);
  k_gather<<<dim3(4, 256), blk, 0, stream>>>(seq, Tbf);
  k_dftm<<<dim3(2, 256), dim3(512), 0, stream>>>(Wdft, Tbf, Xbf);
  k_gram_mfma<<<dim3(4, 128), dim3(64), 0, stream>>>(Tbf, Gpart);
  k_mixm<768><<<dim3(3, 256), dim3(512), 0, stream>>>(Xbf, Wqb, QKV);
  k_scores<<<dim3(8, 128), blk, 0, stream>>>(Xb2, Qb2, Kb2, Spart);
  k_softmax<<<dim3(128), blk, 0, stream>>>(Spart, Gpart, biasb, attn);
  k_build_b<128><<<dim3(2, 256), blk, 0, stream>>>(Wo_s1b, Wob);
  k_sav<<<dim3(16, 16), blk, 0, stream>>>(Xb2, Vb2, attn, SAfb);
  k_mixm<256><<<dim3(1, 256), dim3(512), 0, stream>>>((const u16*)SAfb, Wob,
                                                      OUTb);
  k_transp_out<<<dim3(256), blk, 0, stream>>>((const ushort2*)OUTb,
                                              (ushort2*)OUTt);
  k_irfftm<<<dim3(4, 256), dim3(512), 0, stream>>>(Widf, OUTt, tmpb);
  k_unshift<<<dim3(256), blk, 0, stream>>>(tmpb, out);
}

// Round 11
// 818.643 us; speedup vs baseline: 1.0240x; 1.0240x over previous
//
#include <hip/hip_runtime.h>
#include <hip/hip_bf16.h>
#include <math.h>

// ---------------------------------------------------------------------------
// WinFuncSelfAttention, Fourier-domain.
//   Tbf   bf16 [bs][c][1024p]
//   Wdft  bf16 [512 n=(m,q)][1024 p]
//   Xbf   bf16 [bs][m][256=2c+q]        (bs-major)
//   Wqb   bf16 [m][768][256]
//   QKV   bf16 [nt:3][m][bs][256]       (split Q/K/V)
//   SAfb  bf16 ushort2 [bs][m][128]
//   OUTb  bf16 [m][bs][2c+q]
//   OUTt  bf16 [bs][c][2m+q]
//   Widf  bf16 [1024 p][512 n]
//   tmp   bf16 [bs][p][c]               (final pre-unshift values; |v|<1)
// KEY EMPIRICAL RULES:
//  (R4-R9) HBM write granularity ~= 4KB page per WRITING BLOCK — every
//  destination's aligned 4KB pages must be written entirely by one block.
//  (R10) but the page-fix must not blow LDS/occupancy: keep stages <=48KB.
// ---------------------------------------------------------------------------

#define DEVI __device__ __forceinline__
typedef unsigned short u16;
typedef unsigned int u32;
typedef __attribute__((ext_vector_type(8))) short short8;
typedef __attribute__((ext_vector_type(4))) float f32x4;

DEVI u16 f2b(float f) {
  union { __hip_bfloat16 h; u16 u; } cv;
  cv.h = __float2bfloat16(f);
  return cv.u;
}
DEVI float b2f(u16 u) { return __uint_as_float(((u32)u) << 16); }

// ---------------- K0: bias = attn_mask + log-CPB MLP -----------------------
__global__ __launch_bounds__(256) void k_bias(
    const float* __restrict__ w1, const float* __restrict__ b1,
    const float* __restrict__ w2, const float* __restrict__ amask,
    float* __restrict__ biasb) {
  __shared__ float w1s[1024];
  __shared__ float b1s[512];
  __shared__ float w2s[4096];
  int t = threadIdx.x;
  for (int k = t; k < 1024; k += 256) w1s[k] = w1[k];
  for (int k = t; k < 512; k += 256) b1s[k] = b1[k];
  for (int k = t; k < 4096; k += 256) w2s[k] = w2[k];
  __syncthreads();
  int i = t >> 4, j = t & 15;
  float r0 = (float)((i >> 2) - (j >> 2));
  float r1 = (float)((i & 3) - (j & 3));
  const float sc = 8.0f / 3.0f;  // 8 / log2(8)
  float f0 = (r0 == 0.f) ? 0.f : copysignf(log2f(1.f + fabsf(r0)) * sc, r0);
  float f1 = (r1 == 0.f) ? 0.f : copysignf(log2f(1.f + fabsf(r1)) * sc, r1);
  float o[8];
#pragma unroll
  for (int h = 0; h < 8; h++) o[h] = 0.f;
  for (int k = 0; k < 512; k++) {
    float hd = f0 * w1s[k] + f1 * w1s[512 + k] + b1s[k];
    hd = fmaxf(hd, 0.f);
#pragma unroll
    for (int h = 0; h < 8; h++) o[h] += hd * w2s[k * 8 + h];
  }
  for (int w = 0; w < 4; w++)
#pragma unroll
    for (int h = 0; h < 8; h++) {
      int idx = ((w * 8 + h) * 16 + i) * 16 + j;
      biasb[idx] = amask[idx] + o[h];
    }
}

// ---------------- T: weight transpose wr/wi[c][o][m] -> dst[m][c][o] bf16 --
__global__ __launch_bounds__(256) void k_transpose_wb(
    const float* __restrict__ wr, const float* __restrict__ wi,
    ushort2* __restrict__ dst, int N) {
  __shared__ ushort2 ld[256][17];
  int t = threadIdx.x;
  int ob = blockIdx.x * 16;
  int cb = blockIdx.y * 8;
  for (int cc = 0; cc < 8; cc++) {
    int c = cb + cc;
    for (int oo = 0; oo < 16; oo++) {
      size_t si = ((size_t)c * N + ob + oo) * 256 + t;
      ushort2 u;
      u.x = f2b(wr[si]);
      u.y = f2b(wi[si]);
      ld[t][oo] = u;
    }
    __syncthreads();
    {
      int oo = t & 15, tq = t >> 4;
#pragma unroll
      for (int mr = 0; mr < 16; mr++) {
        int m = mr * 16 + tq;
        dst[((size_t)m * 128 + c) * N + ob + oo] = ld[m][oo];
      }
    }
    __syncthreads();
  }
}

// ---------------- B-build: Ws1[m][c][o] bf16 -> Bt[m][n=2o+p][k=2c+q] ------
template <int N>
__global__ __launch_bounds__(256) void k_build_b(
    const ushort2* __restrict__ Ws1, u16* __restrict__ Bt) {
  __shared__ ushort2 tile[128][65];
  int t = threadIdx.x;
  int ob = blockIdx.x;  // 64-o chunk
  int m = blockIdx.y;
  {
    int c4 = t >> 6, o = t & 63;
    for (int cc = 0; cc < 32; cc++) {
      int c = cc * 4 + c4;
      tile[c][o] = Ws1[((size_t)m * 128 + c) * N + ob * 64 + o];
    }
  }
  __syncthreads();
  int l = t & 63, w2 = t >> 6;
  for (int rr = 0; rr < 32; rr++) {
    int r = w2 * 32 + rr;  // local n row
    int ol = r >> 1, p = r & 1;
    size_t rowoff = ((size_t)m * (2 * N) + (size_t)ob * 128 + r) * 256;
#pragma unroll
    for (int ch = 0; ch < 2; ch++) {
      int c = ch * 64 + l;
      ushort2 wv = tile[c][ol];
      ushort2 u;
      u.x = p ? wv.y : wv.x;
      u.y = p ? wv.x : (u16)(wv.y ^ 0x8000);  // bf16 negate = sign flip
      *(ushort2*)(Bt + rowoff + 2 * c) = u;
    }
  }
}

// ---------------- W-dft build: n=(m,q) rows of cos / -sin ------------------
__global__ __launch_bounds__(256) void k_build_wdft(u16* __restrict__ Wdft) {
  int n = blockIdx.x;  // 0..511
  int m = n >> 1, q = n & 1;
  int kx = m >> 4, ky = m & 15;
  int t = threadIdx.x;
#pragma unroll
  for (int i = 0; i < 4; i++) {
    int p = i * 256 + t;
    int u = p >> 5, v = p & 31;
    int ph = (kx * u + ky * v) & 31;
    float th = 6.283185307179586f * (float)ph / 32.f;
    float sv, cv;
    sincosf(th, &sv, &cv);
    Wdft[(size_t)n * 1024 + p] = f2b(q ? -sv : cv);
  }
}

// ---------------- W-idft build: Widf[p=1024][n=512], c2r + 1/1024 folded ---
__global__ __launch_bounds__(256) void k_build_widft(u16* __restrict__ Widf) {
  int p = blockIdx.x;  // 0..1023
  int x = p >> 5, y = p & 31;
  for (int n = threadIdx.x; n < 512; n += 256) {
    int m = n >> 1, q = n & 1;
    int kx = m >> 4, ky = m & 15;
    int ph = (kx * x + ky * y) & 31;
    float th = 6.283185307179586f * (float)ph / 32.f;
    float sv, cv;
    sincosf(th, &sv, &cv);
    float cky = (ky == 0) ? (1.f / 1024.f) : (2.f / 1024.f);
    Widf[(size_t)p * 512 + n] = f2b(q ? -sv * cky : cv * cky);
  }
}

// ---------------- gather: shifted spatial tiles -> Tbf[bs][c][1024] bf16 ---
__global__ __launch_bounds__(256) void k_gather(
    const float* __restrict__ seq, u16* __restrict__ Tbf) {
  int t = threadIdx.x;
  int cq = blockIdx.x;  // 0..3
  int bs = blockIdx.y;
  int b = bs >> 4, s = bs & 15;
  int qx = s >> 2, qy = s & 3;
  int u = t >> 3, vb = (t & 7) * 4;
  int uu = u + 16;
  int u2 = uu & 31;
  int qx2 = (qx + (uu >> 5)) & 3;
  int vv = vb + 16;
  int v2 = vv & 31;
  int qy2 = (qy + (vv >> 5)) & 3;
  int s2 = qx2 * 4 + qy2;
  size_t srcbase = (((size_t)(b * 16 + s2) * 128) << 10) + u2 * 32 + v2;
  size_t dstbase = (((size_t)bs * 128) << 10) + u * 32 + vb;
  for (int cc = 0; cc < 32; cc++) {
    size_t coff = (size_t)(cq * 32 + cc) << 10;
    float4 v = *(const float4*)(seq + srcbase + coff);
    ushort4 o;
    o.x = f2b(v.x);
    o.y = f2b(v.y);
    o.z = f2b(v.z);
    o.w = f2b(v.w);
    *(ushort4*)(Tbf + dstbase + coff) = o;
  }
}

// ---------------- dftm: per-bs GEMM Wdft[512][1024] @ Tbf[bs][128][1024]^T -
// Output Xbf[bs][m][256]: block writes 64KB contiguous (page-exclusive).
__global__ __launch_bounds__(512) void k_dftm(
    const u16* __restrict__ Wdft, const u16* __restrict__ Tbf,
    u16* __restrict__ Xbf) {
  __shared__ char lds[49152];
  char* As = lds;          // 256 rows x 64k bf16, swizzled
  char* Bs = lds + 32768;  // 128 rows x 64k
  u16* st = (u16*)lds;     // epilogue stage: 64 rows x 264 u16
  int t = threadIdx.x;
  int mt = blockIdx.x, bs = blockIdx.y;
  int l = t & 63, w = t >> 6;
  int wm = w >> 1, wn = w & 1;  // 4x2 wave grid, 64x64 out each
  f32x4 acc[4][4];
#pragma unroll
  for (int a_ = 0; a_ < 4; a_++)
#pragma unroll
    for (int b_ = 0; b_ < 4; b_++) acc[a_][b_] = (f32x4){0.f, 0.f, 0.f, 0.f};
  const u16* Ab = Wdft + (size_t)mt * 256 * 1024;
  const u16* Bb = Tbf + (size_t)bs * 128 * 1024;
  int srow = t >> 3, ss = t & 7;  // srow 0..63
  uint4 ra[4], rb[2];
#pragma unroll
  for (int i = 0; i < 4; i++)
    ra[i] = *(const uint4*)(Ab + (size_t)(i * 64 + srow) * 1024 + ss * 8);
#pragma unroll
  for (int i = 0; i < 2; i++)
    rb[i] = *(const uint4*)(Bb + (size_t)(i * 64 + srow) * 1024 + ss * 8);
  for (int kt = 0; kt < 16; kt++) {
    if (kt) __syncthreads();
#pragma unroll
    for (int i = 0; i < 4; i++) {
      int row = i * 64 + srow;
      *(uint4*)(As + row * 128 + ((ss ^ (row & 7)) << 4)) = ra[i];
    }
#pragma unroll
    for (int i = 0; i < 2; i++) {
      int row = i * 64 + srow;
      *(uint4*)(Bs + row * 128 + ((ss ^ (row & 7)) << 4)) = rb[i];
    }
    if (kt < 15) {
#pragma unroll
      for (int i = 0; i < 4; i++)
        ra[i] = *(const uint4*)(Ab + (size_t)(i * 64 + srow) * 1024 +
                                (kt + 1) * 64 + ss * 8);
#pragma unroll
      for (int i = 0; i < 2; i++)
        rb[i] = *(const uint4*)(Bb + (size_t)(i * 64 + srow) * 1024 +
                                (kt + 1) * 64 + ss * 8);
    }
    __syncthreads();
#pragma unroll
    for (int kk = 0; kk < 2; kk++) {
      short8 af[4], bg[4];
#pragma unroll
      for (int fm = 0; fm < 4; fm++) {
        int row = wm * 64 + fm * 16 + (l & 15);
        int chunk = kk * 4 + (l >> 4);
        af[fm] = *(const short8*)(As + row * 128 + ((chunk ^ (row & 7)) << 4));
      }
#pragma unroll
      for (int fn = 0; fn < 4; fn++) {
        int row = wn * 64 + fn * 16 + (l & 15);
        int chunk = kk * 4 + (l >> 4);
        bg[fn] = *(const short8*)(Bs + row * 128 + ((chunk ^ (row & 7)) << 4));
      }
#pragma unroll
      for (int fm = 0; fm < 4; fm++)
#pragma unroll
        for (int fn = 0; fn < 4; fn++)
          acc[fm][fn] = __builtin_amdgcn_mfma_f32_16x16x32_bf16(
              af[fm], bg[fn], acc[fm][fn], 0, 0, 0);
    }
  }
  // epilogue: 2 passes of 64 m-rows; Xbf[bs][m][256] contiguous stores.
  int cr = (l >> 4) * 4, ccol = l & 15;
  for (int pass = 0; pass < 2; pass++) {
    __syncthreads();
    if ((wm >> 1) == pass) {
#pragma unroll
      for (int fm = 0; fm < 4; fm++) {
#pragma unroll
        for (int fn = 0; fn < 4; fn++) {
          int c = wn * 64 + fn * 16 + ccol;
#pragma unroll
          for (int rp = 0; rp < 4; rp += 2) {
            int rloc = (wm & 1) * 32 + fm * 8 + ((cr + rp) >> 1);
            ushort2 ub;
            ub.x = f2b(acc[fm][fn][rp]);
            ub.y = f2b(acc[fm][fn][rp + 1]);
            *(ushort2*)(st + rloc * 264 + 2 * c) = ub;
          }
        }
      }
    }
    __syncthreads();
#pragma unroll
    for (int it = 0; it < 4; it++) {
      int idx = it * 512 + t;  // 0..2047
      int row = idx >> 5;      // m_local within pass
      int ch = idx & 31;
      uint4 v = *(const uint4*)(st + row * 264 + ch * 8);
      int m = mt * 128 + pass * 64 + row;
      *(uint4*)(Xbf + ((size_t)bs * 256 + m) * 256 + ch * 8) = v;
    }
  }
}

// ---------------- Gram via MFMA: G[b,h] = X X^T over (4ch x 1024p) ---------
__global__ __launch_bounds__(64) void k_gram_mfma(
    const u16* __restrict__ Tbf, float* __restrict__ Gpart) {
  int dc = blockIdx.x;  // 0..3 channel quarter
  int bh = blockIdx.y;  // 0..127
  int b = bh >> 3, h = bh & 7;
  int l = threadIdx.x;  // 0..63
  f32x4 a0 = (f32x4){0.f, 0.f, 0.f, 0.f};
  f32x4 a1 = (f32x4){0.f, 0.f, 0.f, 0.f};
  const u16* base =
      Tbf + ((size_t)(b * 16 + (l & 15)) * 128 + h * 16 + dc * 4) * 1024;
  int ko = (l >> 4) * 8;
  for (int kk = 0; kk < 128; kk += 2) {
    short8 f0 = *(const short8*)(base + kk * 32 + ko);
    short8 f1 = *(const short8*)(base + kk * 32 + 32 + ko);
    a0 = __builtin_amdgcn_mfma_f32_16x16x32_bf16(f0, f0, a0, 0, 0, 0);
    a1 = __builtin_amdgcn_mfma_f32_16x16x32_bf16(f1, f1, a1, 0, 0, 0);
  }
  float* dst = Gpart + ((size_t)(dc * 16 + b) * 8 + h) * 256;
#pragma unroll
  for (int r = 0; r < 4; r++)
    dst[((l >> 4) * 4 + r) * 16 + (l & 15)] = a0[r] + a1[r];
}

// ---------------- MFMA per-mode GEMM: C = A (bs-major) @ B[m]' -------------
// A = [bs][m][256] bf16; out [nt][m][bs][256] (block-exclusive 128KB).
template <int NP>
__global__ __launch_bounds__(512) void k_mixm(
    const u16* __restrict__ A, const u16* __restrict__ Bm,
    u16* __restrict__ Cb) {
  __shared__ char lds[65536];
  char* As = lds;          // 256 rows (bs) x 64 k bf16, swizzled
  char* Bs = lds + 32768;  // 256 rows (n)  x 64 k
  u16* st = (u16*)lds;     // epilogue stage: 64 rows x 264 u16 (pad 8)
  int t = threadIdx.x;
  const int gx = NP / 256;
  int orig = blockIdx.y * gx + blockIdx.x;
  const int tot = gx * 256;
  int lid = (orig & 7) * (tot >> 3) + (orig >> 3);  // XCD-chunked (tot%8==0)
  int nt = lid % gx;
  int m = lid / gx;
  int l = t & 63, w = t >> 6;
  int wm = w >> 1, wn = w & 1;  // wave tile: 64 bs x 128 n
  f32x4 acc[4][8];
#pragma unroll
  for (int a_ = 0; a_ < 4; a_++)
#pragma unroll
    for (int b_ = 0; b_ < 8; b_++) acc[a_][b_] = (f32x4){0.f, 0.f, 0.f, 0.f};
  const u16* Bb = Bm + ((size_t)m * NP + nt * 256) * 256;
  int srow = t >> 3, ss = t & 7;  // srow 0..63, ss = k-chunk
  uint4 ra[4], rb[4];
#pragma unroll
  for (int i = 0; i < 4; i++) {
    int row = i * 64 + srow;
    ra[i] = *(const uint4*)(A + ((size_t)row * 256 + m) * 256 + ss * 8);
    rb[i] = *(const uint4*)(Bb + (size_t)row * 256 + ss * 8);
  }
  for (int kt = 0; kt < 4; kt++) {
    if (kt) __syncthreads();
#pragma unroll
    for (int i = 0; i < 4; i++) {
      int row = i * 64 + srow;
      int sw = ((ss ^ (row & 7)) << 4);
      *(uint4*)(As + row * 128 + sw) = ra[i];
      *(uint4*)(Bs + row * 128 + sw) = rb[i];
    }
    if (kt < 3) {
#pragma unroll
      for (int i = 0; i < 4; i++) {
        int row = i * 64 + srow;
        ra[i] = *(const uint4*)(A + ((size_t)row * 256 + m) * 256 +
                                (kt + 1) * 64 + ss * 8);
        rb[i] =
            *(const uint4*)(Bb + (size_t)row * 256 + (kt + 1) * 64 + ss * 8);
      }
    }
    __syncthreads();
#pragma unroll
    for (int kk = 0; kk < 2; kk++) {
      short8 af[4], bg[8];
#pragma unroll
      for (int fm = 0; fm < 4; fm++) {
        int row = wm * 64 + fm * 16 + (l & 15);
        int chunk = kk * 4 + (l >> 4);
        af[fm] = *(const short8*)(As + row * 128 + ((chunk ^ (row & 7)) << 4));
      }
#pragma unroll
      for (int fn = 0; fn < 8; fn++) {
        int row = wn * 128 + fn * 16 + (l & 15);
        int chunk = kk * 4 + (l >> 4);
        bg[fn] = *(const short8*)(Bs + row * 128 + ((chunk ^ (row & 7)) << 4));
      }
#pragma unroll
      for (int fm = 0; fm < 4; fm++)
#pragma unroll
        for (int fn = 0; fn < 8; fn++)
          acc[fm][fn] = __builtin_amdgcn_mfma_f32_16x16x32_bf16(
              bg[fn], af[fm], acc[fm][fn], 0, 0, 0);  // C^T fragments
    }
  }
  // epilogue: per fm, stage 64 bs x 256 n bf16 in LDS, store 512B rows.
#pragma unroll
  for (int fm = 0; fm < 4; fm++) {
    __syncthreads();
    int rloc = wm * 16 + (l & 15);
#pragma unroll
    for (int fn = 0; fn < 8; fn++) {
      int col = wn * 128 + fn * 16 + (l >> 4) * 4;
      ushort4 u;
      u.x = f2b(acc[fm][fn][0]);
      u.y = f2b(acc[fm][fn][1]);
      u.z = f2b(acc[fm][fn][2]);
      u.w = f2b(acc[fm][fn][3]);
      *(ushort4*)(st + rloc * 264 + col) = u;
    }
    __syncthreads();
#pragma unroll
    for (int it = 0; it < 4; it++) {
      int idx = it * 512 + t;  // 0..2047
      int row = idx >> 5;      // 0..63
      int ch = idx & 31;       // 16B chunk within 512B row
      uint4 v = *(const uint4*)(st + row * 264 + ch * 8);
      int bs = (row >> 4) * 64 + fm * 16 + (row & 15);
      *(uint4*)(Cb + ((size_t)nt * 65536 + (size_t)m * 256 + bs) * 256 +
                ch * 8) = v;
    }
  }
}

// ---------------- transpose: OUTb[m][bs][2c+q] -> OUTt[bs][c][2m+q] --------
__global__ __launch_bounds__(256) void k_transp_out(
    const ushort2* __restrict__ OUTb2, ushort2* __restrict__ OUTt2) {
  __shared__ ushort2 ld[128][129];
  int t = threadIdx.x;
  int bs = blockIdx.x;
  for (int mh = 0; mh < 2; mh++) {
    if (mh) __syncthreads();
    {
      int cidx = t & 127;
      int rb = t >> 7;
      for (int pass = 0; pass < 64; pass++) {
        int r = pass * 2 + rb;
        ld[r][cidx] = OUTb2[((size_t)(mh * 128 + r) * 256 + bs) * 128 + cidx];
      }
    }
    __syncthreads();
    {
      int ml = t & 127;
      int cb = t >> 7;
      for (int pass = 0; pass < 64; pass++) {
        int c = pass * 2 + cb;
        OUTt2[((size_t)bs * 128 + c) * 256 + mh * 128 + ml] = ld[ml][c];
      }
    }
  }
}

// ---------------- irfftm: tmp[bs][p][c] bf16 = Widf @ OUTt -----------------
// Page-exclusive writes AND 48KB LDS (3 blocks/CU): stage [128 p][136 c] bf16.
__global__ __launch_bounds__(512) void k_irfftm(
    const u16* __restrict__ Widf, const u16* __restrict__ OUTt,
    u16* __restrict__ tmp) {
  __shared__ char lds[49152];
  char* As = lds;          // 256 p-rows x 64k bf16, swizzled
  char* Bs = lds + 32768;  // 128 c-rows x 64k
  u16* st = (u16*)lds;     // epilogue stage [128][136] bf16 (34,816 B)
  int t = threadIdx.x;
  int ph = blockIdx.x, bs = blockIdx.y;
  int l = t & 63, w = t >> 6;
  int wm = w >> 1, wn = w & 1;  // 4(p) x 2(c) waves, 64x64 out each
  f32x4 acc[4][4];
#pragma unroll
  for (int a_ = 0; a_ < 4; a_++)
#pragma unroll
    for (int b_ = 0; b_ < 4; b_++) acc[a_][b_] = (f32x4){0.f, 0.f, 0.f, 0.f};
  const u16* Ab = Widf + (size_t)ph * 256 * 512;
  const u16* Bb = OUTt + (size_t)bs * 128 * 512;
  int srow = t >> 3, ss = t & 7;
  uint4 ra[4], rb[2];
#pragma unroll
  for (int i = 0; i < 4; i++)
    ra[i] = *(const uint4*)(Ab + (size_t)(i * 64 + srow) * 512 + ss * 8);
#pragma unroll
  for (int i = 0; i < 2; i++)
    rb[i] = *(const uint4*)(Bb + (size_t)(i * 64 + srow) * 512 + ss * 8);
  for (int kt = 0; kt < 8; kt++) {
    if (kt) __syncthreads();
#pragma unroll
    for (int i = 0; i < 4; i++) {
      int row = i * 64 + srow;
      *(uint4*)(As + row * 128 + ((ss ^ (row & 7)) << 4)) = ra[i];
    }
#pragma unroll
    for (int i = 0; i < 2; i++) {
      int row = i * 64 + srow;
      *(uint4*)(Bs + row * 128 + ((ss ^ (row & 7)) << 4)) = rb[i];
    }
    if (kt < 7) {
#pragma unroll
      for (int i = 0; i < 4; i++)
        ra[i] = *(const uint4*)(Ab + (size_t)(i * 64 + srow) * 512 +
                                (kt + 1) * 64 + ss * 8);
#pragma unroll
      for (int i = 0; i < 2; i++)
        rb[i] = *(const uint4*)(Bb + (size_t)(i * 64 + srow) * 512 +
                                (kt + 1) * 64 + ss * 8);
    }
    __syncthreads();
#pragma unroll
    for (int kk = 0; kk < 2; kk++) {
      short8 wf[4], bg[4];
#pragma unroll
      for (int fm = 0; fm < 4; fm++) {
        int row = wm * 64 + fm * 16 + (l & 15);
        int chunk = kk * 4 + (l >> 4);
        wf[fm] = *(const short8*)(As + row * 128 + ((chunk ^ (row & 7)) << 4));
      }
#pragma unroll
      for (int fn = 0; fn < 4; fn++) {
        int row = wn * 64 + fn * 16 + (l & 15);
        int chunk = kk * 4 + (l >> 4);
        bg[fn] = *(const short8*)(Bs + row * 128 + ((chunk ^ (row & 7)) << 4));
      }
#pragma unroll
      for (int fm = 0; fm < 4; fm++)
#pragma unroll
        for (int fn = 0; fn < 4; fn++)
          acc[fm][fn] = __builtin_amdgcn_mfma_f32_16x16x32_bf16(
              wf[fm], bg[fn], acc[fm][fn], 0, 0, 0);  // row=p, col=c
    }
  }
  // epilogue: two passes of 128 p-rows; stage [pl][c] bf16, 256B-row stores.
  for (int pass = 0; pass < 2; pass++) {
    __syncthreads();
    if ((wm >> 1) == pass) {
#pragma unroll
      for (int fm = 0; fm < 4; fm++)
#pragma unroll
        for (int fn = 0; fn < 4; fn++) {
          int c = wn * 64 + fn * 16 + (l & 15);
#pragma unroll
          for (int r = 0; r < 4; r++) {
            int pl = (wm & 1) * 64 + fm * 16 + (l >> 4) * 4 + r;
            st[pl * 136 + c] = f2b(acc[fm][fn][r]);
          }
        }
    }
    __syncthreads();
#pragma unroll
    for (int it = 0; it < 4; it++) {
      int idx = it * 512 + t;  // 0..2047 16B chunks
      int row = idx >> 4;      // 0..127 p-local
      int ch = idx & 15;
      uint4 v = *(const uint4*)(st + row * 136 + ch * 8);
      int p = ph * 256 + pass * 128 + row;
      *(uint4*)(tmp + ((size_t)bs * 1024 + p) * 128 + ch * 8) = v;
    }
  }
}

// ---------------- unshift: out[bs2][c][u2][v2] = b2f(tmp[bs_src][x,y][c]) --
// Grid (4 c-quarters, 256 bs2); blocks own whole (bs2,c) 4KB output planes.
__global__ __launch_bounds__(256) void k_unshift(
    const u16* __restrict__ tmp, float* __restrict__ out) {
  __shared__ float ld[2][32][33];
  int t = threadIdx.x;
  int cq = blockIdx.x;
  int bs2 = blockIdx.y;
  int b = bs2 >> 4, s2 = bs2 & 15;
  int qx2 = s2 >> 2, qy2 = s2 & 3;
  int r = t >> 3;  // load-side v2 row
  int y = (r < 16) ? r + 16 : r - 16;
  int qy = (r < 16) ? (qy2 + 3) & 3 : qy2;
  int cl4 = (t & 7) * 4;  // load-side c chunk
  int cs = t >> 3;        // store-side c_local
  int vh = (t & 7) * 4;   // store-side v2 base
  for (int u2 = 0; u2 < 32; u2++) {
    int cu = u2 & 1;
    int x = (u2 < 16) ? u2 + 16 : u2 - 16;
    int qx = (u2 < 16) ? (qx2 + 3) & 3 : qx2;
    {
      int bs_src = b * 16 + qx * 4 + qy;
      const u16* src =
          tmp + ((size_t)bs_src * 1024 + x * 32 + y) * 128 + cq * 32;
      ushort4 v = *(const ushort4*)(src + cl4);
      ld[cu][r][cl4 + 0] = b2f(v.x);
      ld[cu][r][cl4 + 1] = b2f(v.y);
      ld[cu][r][cl4 + 2] = b2f(v.z);
      ld[cu][r][cl4 + 3] = b2f(v.w);
    }
    __syncthreads();
    {
      float* dst =
          out + (((size_t)bs2 * 128 + cq * 32 + cs) << 10) + u2 * 32 + vh;
      float4 v = make_float4(ld[cu][vh + 0][cs], ld[cu][vh + 1][cs],
                             ld[cu][vh + 2][cs], ld[cu][vh + 3][cs]);
      *(float4*)dst = v;
    }
  }
}

// ---------------- K3: score partials over low modes ------------------------
__global__ __launch_bounds__(256) void k_scores(
    const ushort2* __restrict__ Xb2, const ushort2* __restrict__ Qb2,
    const ushort2* __restrict__ Kb2, float* __restrict__ Spart) {
  __shared__ float2 Xs[16][17], Qs[16][17], Ks[16][17];
  int t = threadIdx.x;
  int mc = blockIdx.x;
  int bh = blockIdx.y;
  int b = bh >> 3, h = bh & 7;
  int i = t >> 4, j = t & 15;
  int bs = b * 16 + i;
  int d = j;
  int m0 = mc * 32;
  size_t xoff = ((size_t)bs * 256 + m0) * 128 + h * 16 + d;
  size_t qoff = ((size_t)m0 * 256 + bs) * 128 + h * 16 + d;
  ushort2 ux = Xb2[xoff];
  ushort2 uq = Qb2[qoff];
  ushort2 uk = Kb2[qoff];
  float acc = 0.f;
  for (int mm = 0; mm < 32; mm++) {
    int m = m0 + mm;
    Xs[i][d] = make_float2(b2f(ux.x), b2f(ux.y));
    Qs[i][d] = make_float2(b2f(uq.x), b2f(uq.y));
    Ks[i][d] = make_float2(b2f(uk.x), b2f(uk.y));
    __syncthreads();
    if (mm < 31) {
      ux = Xb2[xoff + (size_t)(mm + 1) * 128];
      uq = Qb2[qoff + (size_t)(mm + 1) * 32768];
      uk = Kb2[qoff + (size_t)(mm + 1) * 32768];
    }
    int ky = m & 15, kx = m >> 4;
    if (ky > 0) {
#pragma unroll
      for (int dd = 0; dd < 16; dd++) {
        float2 Xi = Xs[i][dd], Qi = Qs[i][dd], Xj = Xs[j][dd], Kj = Ks[j][dd];
        float qr = Xi.x + Qi.x, qi = Xi.y + Qi.y;
        float kr = Xj.x + Kj.x, ki = Xj.y + Kj.y;
        acc += 2.f * (qr * kr + qi * ki - (Xi.x * Xj.x + Xi.y * Xj.y));
      }
    } else {
#pragma unroll
      for (int dd = 0; dd < 16; dd++) {
        float2 Xi = Xs[i][dd], Qi = Qs[i][dd], Xj = Xs[j][dd], Kj = Ks[j][dd];
        float cr = Xi.x * Kj.x + Xi.y * Kj.y + Qi.x * Xj.x + Qi.y * Xj.y;
        float qk =
            (kx == 0) ? (Qi.x * Kj.x) : 0.5f * (Qi.x * Kj.x + Qi.y * Kj.y);
        acc += cr + qk;
      }
    }
    __syncthreads();
  }
  Spart[((size_t)mc * 128 + bh) * 256 + t] = acc;
}

// ---------------- K3b: assemble scores, bias, softmax ----------------------
__global__ __launch_bounds__(256) void k_softmax(
    const float* __restrict__ Spart, const float* __restrict__ Gpart,
    const float* __restrict__ biasb, float* __restrict__ attn) {
  int t = threadIdx.x;
  int bh = blockIdx.x;
  int b = bh >> 3, h = bh & 7;
  int i = t >> 4, j = t & 15;
  float acc = 0.f;
#pragma unroll
  for (int mc = 0; mc < 8; mc++)
    acc += Spart[((size_t)mc * 128 + bh) * 256 + t];
  float G = 0.f;
#pragma unroll
  for (int dc = 0; dc < 4; dc++)
    G += Gpart[((size_t)(dc * 16 + b) * 8 + h) * 256 + t];
  float score = G * (1.f / 4096.f) + acc * (1.f / 4194304.f) +
                biasb[(((b & 3) * 8 + h) * 16 + i) * 16 + j];
  float mx = score;
#pragma unroll
  for (int o = 8; o >= 1; o >>= 1) mx = fmaxf(mx, __shfl_xor(mx, o, 16));
  float e = expf(score - mx);
  float sm = e;
#pragma unroll
  for (int o = 8; o >= 1; o >>= 1) sm += __shfl_xor(sm, o, 16);
  attn[(size_t)bh * 256 + t] = e / sm;
}

// ---------------- K4: SAf[bs][m][c] = attn @ (X + Vm~)  (bf16 out) ---------
__global__ __launch_bounds__(256) void k_sav(
    const ushort2* __restrict__ Xb2, const ushort2* __restrict__ Vb2,
    const float* __restrict__ attn, ushort2* __restrict__ SAfb) {
  __shared__ float at[8][16][17];
  __shared__ float2 vt[16][130];
  int t = threadIdx.x;
  int mc = blockIdx.x;
  int b = blockIdx.y;
  {
    int h = t >> 5, ii = (t >> 1) & 15, jb = (t & 1) * 8;
#pragma unroll
    for (int k = 0; k < 8; k++)
      at[h][ii][jb + k] = attn[((size_t)(b * 8 + h) * 16 + ii) * 16 + jb + k];
  }
  __syncthreads();
  int i = t >> 4, cg = t & 15;
  for (int mm = 0; mm < 16; mm++) {
    int m = mc * 16 + mm;
    int ky = m & 15, kx = m >> 4;
    {
      int jj = t >> 4;
      size_t vrow = ((size_t)m * 256 + b * 16 + jj) * 128;
      size_t xrow = ((size_t)(b * 16 + jj) * 256 + m) * 128;
#pragma unroll
      for (int u = 0; u < 8; u++) {
        int c = cg + u * 16;
        ushort2 uv = Vb2[vrow + c];
        float2 vm = make_float2(b2f(uv.x), b2f(uv.y));
        ushort2 uxv = Xb2[xrow + c];
        float2 xv = make_float2(b2f(uxv.x), b2f(uxv.y));
        float2 vh;
        if (ky == 0) {
          if (kx == 0)
            vh = make_float2(xv.x + vm.x, xv.y);
          else
            vh = make_float2(xv.x + 0.5f * vm.x, xv.y + 0.5f * vm.y);
        } else
          vh = make_float2(xv.x + vm.x, xv.y + vm.y);
        vt[jj][c] = vh;
      }
    }
    __syncthreads();
    float2 o8[8];
#pragma unroll
    for (int u = 0; u < 8; u++) o8[u] = make_float2(0.f, 0.f);
#pragma unroll
    for (int jj = 0; jj < 16; jj++) {
#pragma unroll
      for (int u = 0; u < 8; u++) {
        float av = at[u][i][jj];
        float2 v = vt[jj][cg + u * 16];
        o8[u].x += av * v.x;
        o8[u].y += av * v.y;
      }
    }
    size_t orow = ((size_t)(b * 16 + i) * 256 + m) * 128;  // [bs][m][128]
#pragma unroll
    for (int u = 0; u < 8; u++) {
      ushort2 ub;
      ub.x = f2b(o8[u].x);
      ub.y = f2b(o8[u].y);
      SAfb[orow + cg + u * 16] = ub;
    }
    __syncthreads();
  }
}

// ---------------------------------------------------------------------------
extern "C" void kernel_launch(void* const* d_in, const int* in_sizes, int n_in,
                              void* d_out, int out_size, void* d_ws,
                              size_t ws_size, hipStream_t stream) {
  (void)in_sizes;
  (void)n_in;
  const float* seq = (const float*)d_in[0];
  const float* qwr = (const float*)d_in[1];
  const float* qwi = (const float*)d_in[2];
  const float* owr = (const float*)d_in[3];
  const float* owi = (const float*)d_in[4];
  const float* cw1 = (const float*)d_in[5];
  const float* cb1 = (const float*)d_in[6];
  const float* cw2 = (const float*)d_in[7];
  const float* amask = (const float*)d_in[8];
  float* out = (float*)d_out;
  char* ws = (char*)d_ws;

  const size_t R = 100663296;  // 96 MiB region
  // R1: Wq_s1b (50.3MB) -> Tbf (67MB) + Xbf (33.5MB); Wob aliases Tbf
  ushort2* Wq_s1b = (ushort2*)ws;
  u16* Tbf = (u16*)ws;
  u16* Xbf = (u16*)(ws + 67108864);  // [bs][m][256]
  ushort2* Xb2 = (ushort2*)Xbf;
  u16* Wob = (u16*)ws;
  // R2: QKV [3][m][bs][256] (100.6MB) -> after sav: OUTb + OUTt
  u16* QKV = (u16*)(ws + R);
  ushort2* Qb2 = (ushort2*)QKV;
  ushort2* Kb2 = Qb2 + 8388608;
  ushort2* Vb2 = Qb2 + 16777216;
  u16* OUTb = (u16*)(ws + R);
  u16* OUTt = (u16*)(ws + R + 33554432);
  // tmp bf16 [bs][p][c] = 64 MiB at [160 MiB, 224 MiB)
  u16* tmpb = (u16*)(ws + R + 2 * 33554432);
  // R3: Wqb (100.6MB) -> SAfb (33.5MB) after mix1
  u16* Wqb = (u16*)(ws + 2 * R);
  ushort2* SAfb = (ushort2*)(ws + 2 * R);
  // R4: Wo_s1b bf16 (16.8MB)
  ushort2* Wo_s1b = (ushort2*)(ws + 3 * R);
  char* sm = ws + 3 * R + 16777216 + 67108864;
  u16* Wdft = (u16*)sm;                   // 1,048,576
  float* Gpart = (float*)(sm + 1048576);  // 524,288
  float* biasb = (float*)(sm + 1572864);  // 32,768
  float* attn = (float*)(sm + 1605632);   // 131,072
  float* Spart = (float*)(sm + 1736704);  // 1,048,576
  u16* Widf = (u16*)(sm + 2785280);       // 1,048,576
  size_t need = 3 * R + 16777216 + 67108864 + 2785280 + 1048576;

  if (ws_size < need) {
    hipMemsetAsync(d_out, 0, (size_t)out_size * 4, stream);
    return;
  }

  dim3 blk(256);
  k_transpose_wb<<<dim3(24, 16), blk, 0, stream>>>(qwr, qwi, Wq_s1b, 384);
  k_build_b<384><<<dim3(6, 256), blk, 0, stream>>>(Wq_s1b, Wqb);
  k_transpose_wb<<<dim3(8, 16), blk, 0, stream>>>(owr, owi, Wo_s1b, 128);
  k_bias<<<dim3(1), blk, 0, stream>>>(cw1, cb1, cw2, amask, biasb);
  k_build_wdft<<<dim3(512), blk, 0, stream>>>(Wdft);
  k_build_widft<<<dim3(1024), blk, 0, stream>>>(Widf);
  k_gather<<<dim3(4, 256), blk, 0, stream>>>(seq, Tbf);
  k_dftm<<<dim3(2, 256), dim3(512), 0, stream>>>(Wdft, Tbf, Xbf);
  k_gram_mfma<<<dim3(4, 128), dim3(64), 0, stream>>>(Tbf, Gpart);
  k_mixm<768><<<dim3(3, 256), dim3(512), 0, stream>>>(Xbf, Wqb, QKV);
  k_scores<<<dim3(8, 128), blk, 0, stream>>>(Xb2, Qb2, Kb2, Spart);
  k_softmax<<<dim3(128), blk, 0, stream>>>(Spart, Gpart, biasb, attn);
  k_build_b<128><<<dim3(2, 256), blk, 0, stream>>>(Wo_s1b, Wob);
  k_sav<<<dim3(16, 16), blk, 0, stream>>>(Xb2, Vb2, attn, SAfb);
  k_mixm<256><<<dim3(1, 256), dim3(512), 0, stream>>>((const u16*)SAfb, Wob,
                                                      OUTb);
  k_transp_out<<<dim3(256), blk, 0, stream>>>((const ushort2*)OUTb,
                                              (ushort2*)OUTt);
  k_irfftm<<<dim3(4, 256), dim3(512), 0, stream>>>(Widf, OUTt, tmpb);
  k_unshift<<<dim3(4, 256), blk, 0, stream>>>(tmpb, out);
}

// Round 12
// 792.418 us; speedup vs baseline: 1.0579x; 1.0331x over previous
//
#include <hip/hip_runtime.h>
#include <hip/hip_bf16.h>
#include <math.h>

// ---------------------------------------------------------------------------
// WinFuncSelfAttention, Fourier-domain.
//   Wdft  bf16 [512 n=(m,q)][1024 p]
//   Xbf   bf16 [bs][m][256=2c+q]        (bs-major)
//   Wqb   bf16 [m][768][256]
//   QKV   bf16 [nt:3][m][bs][256]       (split Q/K/V)
//   SAfb  bf16 ushort2 [bs][m][128]
//   OUTb  bf16 [m][bs][2c+q]
//   OUTt  bf16 [bs][c][2m+q]
//   Widf  bf16 [1024 p][512 n]
//   tmp   bf16 [bs][p][c]
// KEY EMPIRICAL MODEL (R11): per-dispatch WRITE_SIZE is smeared lazy-writeback
// of earlier kernels' dirty L3 — the pipeline is GLOBALLY HBM-bound. Optimize
// TOTAL bytes. This round: shift-gather fused into dftm/gram (Tbf deleted);
// every 8-elem k-chunk is contiguous in seq because 8 | 16 (shift granule).
// ---------------------------------------------------------------------------

#define DEVI __device__ __forceinline__
typedef unsigned short u16;
typedef unsigned int u32;
typedef __attribute__((ext_vector_type(8))) short short8;
typedef __attribute__((ext_vector_type(4))) float f32x4;

DEVI u16 f2b(float f) {
  union { __hip_bfloat16 h; u16 u; } cv;
  cv.h = __float2bfloat16(f);
  return cv.u;
}
DEVI float b2f(u16 u) { return __uint_as_float(((u32)u) << 16); }
DEVI u32 pk2(float a, float b) {
  return (u32)f2b(a) | ((u32)f2b(b) << 16);
}

// ---------------- K0: bias = attn_mask + log-CPB MLP -----------------------
__global__ __launch_bounds__(256) void k_bias(
    const float* __restrict__ w1, const float* __restrict__ b1,
    const float* __restrict__ w2, const float* __restrict__ amask,
    float* __restrict__ biasb) {
  __shared__ float w1s[1024];
  __shared__ float b1s[512];
  __shared__ float w2s[4096];
  int t = threadIdx.x;
  for (int k = t; k < 1024; k += 256) w1s[k] = w1[k];
  for (int k = t; k < 512; k += 256) b1s[k] = b1[k];
  for (int k = t; k < 4096; k += 256) w2s[k] = w2[k];
  __syncthreads();
  int i = t >> 4, j = t & 15;
  float r0 = (float)((i >> 2) - (j >> 2));
  float r1 = (float)((i & 3) - (j & 3));
  const float sc = 8.0f / 3.0f;  // 8 / log2(8)
  float f0 = (r0 == 0.f) ? 0.f : copysignf(log2f(1.f + fabsf(r0)) * sc, r0);
  float f1 = (r1 == 0.f) ? 0.f : copysignf(log2f(1.f + fabsf(r1)) * sc, r1);
  float o[8];
#pragma unroll
  for (int h = 0; h < 8; h++) o[h] = 0.f;
  for (int k = 0; k < 512; k++) {
    float hd = f0 * w1s[k] + f1 * w1s[512 + k] + b1s[k];
    hd = fmaxf(hd, 0.f);
#pragma unroll
    for (int h = 0; h < 8; h++) o[h] += hd * w2s[k * 8 + h];
  }
  for (int w = 0; w < 4; w++)
#pragma unroll
    for (int h = 0; h < 8; h++) {
      int idx = ((w * 8 + h) * 16 + i) * 16 + j;
      biasb[idx] = amask[idx] + o[h];
    }
}

// ---------------- T: weight transpose wr/wi[c][o][m] -> dst[m][c][o] bf16 --
__global__ __launch_bounds__(256) void k_transpose_wb(
    const float* __restrict__ wr, const float* __restrict__ wi,
    ushort2* __restrict__ dst, int N) {
  __shared__ ushort2 ld[256][17];
  int t = threadIdx.x;
  int ob = blockIdx.x * 16;
  int cb = blockIdx.y * 8;
  for (int cc = 0; cc < 8; cc++) {
    int c = cb + cc;
    for (int oo = 0; oo < 16; oo++) {
      size_t si = ((size_t)c * N + ob + oo) * 256 + t;
      ushort2 u;
      u.x = f2b(wr[si]);
      u.y = f2b(wi[si]);
      ld[t][oo] = u;
    }
    __syncthreads();
    {
      int oo = t & 15, tq = t >> 4;
#pragma unroll
      for (int mr = 0; mr < 16; mr++) {
        int m = mr * 16 + tq;
        dst[((size_t)m * 128 + c) * N + ob + oo] = ld[m][oo];
      }
    }
    __syncthreads();
  }
}

// ---------------- B-build: Ws1[m][c][o] bf16 -> Bt[m][n=2o+p][k=2c+q] ------
template <int N>
__global__ __launch_bounds__(256) void k_build_b(
    const ushort2* __restrict__ Ws1, u16* __restrict__ Bt) {
  __shared__ ushort2 tile[128][65];
  int t = threadIdx.x;
  int ob = blockIdx.x;  // 64-o chunk
  int m = blockIdx.y;
  {
    int c4 = t >> 6, o = t & 63;
    for (int cc = 0; cc < 32; cc++) {
      int c = cc * 4 + c4;
      tile[c][o] = Ws1[((size_t)m * 128 + c) * N + ob * 64 + o];
    }
  }
  __syncthreads();
  int l = t & 63, w2 = t >> 6;
  for (int rr = 0; rr < 32; rr++) {
    int r = w2 * 32 + rr;  // local n row
    int ol = r >> 1, p = r & 1;
    size_t rowoff = ((size_t)m * (2 * N) + (size_t)ob * 128 + r) * 256;
#pragma unroll
    for (int ch = 0; ch < 2; ch++) {
      int c = ch * 64 + l;
      ushort2 wv = tile[c][ol];
      ushort2 u;
      u.x = p ? wv.y : wv.x;
      u.y = p ? wv.x : (u16)(wv.y ^ 0x8000);  // bf16 negate = sign flip
      *(ushort2*)(Bt + rowoff + 2 * c) = u;
    }
  }
}

// ---------------- W-dft build: n=(m,q) rows of cos / -sin ------------------
__global__ __launch_bounds__(256) void k_build_wdft(u16* __restrict__ Wdft) {
  int n = blockIdx.x;  // 0..511
  int m = n >> 1, q = n & 1;
  int kx = m >> 4, ky = m & 15;
  int t = threadIdx.x;
#pragma unroll
  for (int i = 0; i < 4; i++) {
    int p = i * 256 + t;
    int u = p >> 5, v = p & 31;
    int ph = (kx * u + ky * v) & 31;
    float th = 6.283185307179586f * (float)ph / 32.f;
    float sv, cv;
    sincosf(th, &sv, &cv);
    Wdft[(size_t)n * 1024 + p] = f2b(q ? -sv : cv);
  }
}

// ---------------- W-idft build: Widf[p=1024][n=512], c2r + 1/1024 folded ---
__global__ __launch_bounds__(256) void k_build_widft(u16* __restrict__ Widf) {
  int p = blockIdx.x;  // 0..1023
  int x = p >> 5, y = p & 31;
  for (int n = threadIdx.x; n < 512; n += 256) {
    int m = n >> 1, q = n & 1;
    int kx = m >> 4, ky = m & 15;
    int ph = (kx * x + ky * y) & 31;
    float th = 6.283185307179586f * (float)ph / 32.f;
    float sv, cv;
    sincosf(th, &sv, &cv);
    float cky = (ky == 0) ? (1.f / 1024.f) : (2.f / 1024.f);
    Widf[(size_t)p * 512 + n] = f2b(q ? -sv * cky : cv * cky);
  }
}

// ---------------- dftm: per-bs GEMM Wdft[512][1024] @ shifted(seq)^T -------
// B-operand loaded DIRECTLY from fp32 seq with fused shift addressing
// (each 8-elem k-chunk is contiguous in seq; bf16 convert in-register —
// bit-identical to the old gather+Tbf path). Xbf[bs][m][256] block-owned.
__global__ __launch_bounds__(512) void k_dftm(
    const u16* __restrict__ Wdft, const float* __restrict__ seq,
    u16* __restrict__ Xbf) {
  __shared__ char lds[49152];
  char* As = lds;          // 256 rows x 64k bf16, swizzled
  char* Bs = lds + 32768;  // 128 rows x 64k
  u16* st = (u16*)lds;     // epilogue stage: 64 rows x 264 u16
  int t = threadIdx.x;
  int mt = blockIdx.x, bs = blockIdx.y;
  int b = bs >> 4, s = bs & 15;
  int qx = s >> 2, qy = s & 3;
  int l = t & 63, w = t >> 6;
  int wm = w >> 1, wn = w & 1;  // 4x2 wave grid, 64x64 out each
  f32x4 acc[4][4];
#pragma unroll
  for (int a_ = 0; a_ < 4; a_++)
#pragma unroll
    for (int b_ = 0; b_ < 4; b_++) acc[a_][b_] = (f32x4){0.f, 0.f, 0.f, 0.f};
  const u16* Ab = Wdft + (size_t)mt * 256 * 1024;
  int srow = t >> 3, ss = t & 7;  // srow 0..63
  // B shift addressing: p = kt*64 + ss*8 (+j); v-part is thread-constant.
  int vband = (ss & 3) * 8;
  int vv = vband + 16;
  int v2 = vv & 31;
  int qy2 = (qy + (vv >> 5)) & 3;
  uint4 ra[4];
  float4 rf[2][2];
#pragma unroll
  for (int i = 0; i < 4; i++)
    ra[i] = *(const uint4*)(Ab + (size_t)(i * 64 + srow) * 1024 + ss * 8);
#pragma unroll
  for (int i = 0; i < 2; i++) {
    int c = i * 64 + srow;
    int u = (ss >> 2);  // kt=0
    int uu = u + 16;
    int u2 = uu & 31;
    int qx2 = (qx + (uu >> 5)) & 3;
    const float* src = seq +
                       (((size_t)(b * 16 + qx2 * 4 + qy2) * 128 + c) << 10) +
                       u2 * 32 + v2;
    rf[i][0] = *(const float4*)src;
    rf[i][1] = *(const float4*)(src + 4);
  }
  for (int kt = 0; kt < 16; kt++) {
    if (kt) __syncthreads();
#pragma unroll
    for (int i = 0; i < 4; i++) {
      int row = i * 64 + srow;
      *(uint4*)(As + row * 128 + ((ss ^ (row & 7)) << 4)) = ra[i];
    }
#pragma unroll
    for (int i = 0; i < 2; i++) {
      int row = i * 64 + srow;
      uint4 bv;
      bv.x = pk2(rf[i][0].x, rf[i][0].y);
      bv.y = pk2(rf[i][0].z, rf[i][0].w);
      bv.z = pk2(rf[i][1].x, rf[i][1].y);
      bv.w = pk2(rf[i][1].z, rf[i][1].w);
      *(uint4*)(Bs + row * 128 + ((ss ^ (row & 7)) << 4)) = bv;
    }
    if (kt < 15) {
#pragma unroll
      for (int i = 0; i < 4; i++)
        ra[i] = *(const uint4*)(Ab + (size_t)(i * 64 + srow) * 1024 +
                                (kt + 1) * 64 + ss * 8);
      int u = (kt + 1) * 2 + (ss >> 2);
      int uu = u + 16;
      int u2 = uu & 31;
      int qx2 = (qx + (uu >> 5)) & 3;
      size_t base = (((size_t)(b * 16 + qx2 * 4 + qy2) * 128) << 10) +
                    u2 * 32 + v2;
#pragma unroll
      for (int i = 0; i < 2; i++) {
        int c = i * 64 + srow;
        const float* src = seq + base + ((size_t)c << 10);
        rf[i][0] = *(const float4*)src;
        rf[i][1] = *(const float4*)(src + 4);
      }
    }
    __syncthreads();
#pragma unroll
    for (int kk = 0; kk < 2; kk++) {
      short8 af[4], bg[4];
#pragma unroll
      for (int fm = 0; fm < 4; fm++) {
        int row = wm * 64 + fm * 16 + (l & 15);
        int chunk = kk * 4 + (l >> 4);
        af[fm] = *(const short8*)(As + row * 128 + ((chunk ^ (row & 7)) << 4));
      }
#pragma unroll
      for (int fn = 0; fn < 4; fn++) {
        int row = wn * 64 + fn * 16 + (l & 15);
        int chunk = kk * 4 + (l >> 4);
        bg[fn] = *(const short8*)(Bs + row * 128 + ((chunk ^ (row & 7)) << 4));
      }
#pragma unroll
      for (int fm = 0; fm < 4; fm++)
#pragma unroll
        for (int fn = 0; fn < 4; fn++)
          acc[fm][fn] = __builtin_amdgcn_mfma_f32_16x16x32_bf16(
              af[fm], bg[fn], acc[fm][fn], 0, 0, 0);
    }
  }
  // epilogue: 2 passes of 64 m-rows; Xbf[bs][m][256] contiguous stores.
  int cr = (l >> 4) * 4, ccol = l & 15;
  for (int pass = 0; pass < 2; pass++) {
    __syncthreads();
    if ((wm >> 1) == pass) {
#pragma unroll
      for (int fm = 0; fm < 4; fm++) {
#pragma unroll
        for (int fn = 0; fn < 4; fn++) {
          int c = wn * 64 + fn * 16 + ccol;
#pragma unroll
          for (int rp = 0; rp < 4; rp += 2) {
            int rloc = (wm & 1) * 32 + fm * 8 + ((cr + rp) >> 1);
            ushort2 ub;
            ub.x = f2b(acc[fm][fn][rp]);
            ub.y = f2b(acc[fm][fn][rp + 1]);
            *(ushort2*)(st + rloc * 264 + 2 * c) = ub;
          }
        }
      }
    }
    __syncthreads();
#pragma unroll
    for (int it = 0; it < 4; it++) {
      int idx = it * 512 + t;  // 0..2047
      int row = idx >> 5;      // m_local within pass
      int ch = idx & 31;
      uint4 v = *(const uint4*)(st + row * 264 + ch * 8);
      int m = mt * 128 + pass * 64 + row;
      *(uint4*)(Xbf + ((size_t)bs * 256 + m) * 256 + ch * 8) = v;
    }
  }
}

// ---------------- Gram via MFMA, reading seq with fused shift --------------
// 128 blocks (b,h) x 256 thr; wave w = channel-quarter dc; LDS reduce.
__global__ __launch_bounds__(256) void k_gram_seq(
    const float* __restrict__ seq, float* __restrict__ Gfull) {
  __shared__ float red[3][256];
  int t = threadIdx.x;
  int bh = blockIdx.x;
  int b = bh >> 3, h = bh & 7;
  int w = t >> 6, l = t & 63;
  int tok = l & 15;
  int qx = tok >> 2, qy = tok & 3;
  int ko = (l >> 4) * 8;
  int v2 = (ko < 16) ? ko + 16 : ko - 16;
  int qy2 = (ko < 16) ? qy : (qy + 1) & 3;
  f32x4 a = (f32x4){0.f, 0.f, 0.f, 0.f};
  for (int cc = 0; cc < 4; cc++) {
    int c = h * 16 + w * 4 + cc;
#pragma unroll 4
    for (int u = 0; u < 32; u++) {
      int uu = u + 16;
      int u2 = uu & 31;
      int qx2 = (qx + (uu >> 5)) & 3;
      const float* src = seq +
                         (((size_t)(b * 16 + qx2 * 4 + qy2) * 128 + c) << 10) +
                         u2 * 32 + v2;
      float4 lo = *(const float4*)src;
      float4 hi = *(const float4*)(src + 4);
      union { short8 s8; uint4 u4; } f;
      f.u4.x = pk2(lo.x, lo.y);
      f.u4.y = pk2(lo.z, lo.w);
      f.u4.z = pk2(hi.x, hi.y);
      f.u4.w = pk2(hi.z, hi.w);
      a = __builtin_amdgcn_mfma_f32_16x16x32_bf16(f.s8, f.s8, a, 0, 0, 0);
    }
  }
  if (w > 0) {
#pragma unroll
    for (int r = 0; r < 4; r++)
      red[w - 1][((l >> 4) * 4 + r) * 16 + (l & 15)] = a[r];
  }
  __syncthreads();
  if (w == 0) {
#pragma unroll
    for (int r = 0; r < 4; r++) {
      int idx = ((l >> 4) * 4 + r) * 16 + (l & 15);
      Gfull[(size_t)bh * 256 + idx] =
          a[r] + red[0][idx] + red[1][idx] + red[2][idx];
    }
  }
}

// ---------------- MFMA per-mode GEMM: C = A (bs-major) @ B[m]' -------------
template <int NP>
__global__ __launch_bounds__(512) void k_mixm(
    const u16* __restrict__ A, const u16* __restrict__ Bm,
    u16* __restrict__ Cb) {
  __shared__ char lds[65536];
  char* As = lds;          // 256 rows (bs) x 64 k bf16, swizzled
  char* Bs = lds + 32768;  // 256 rows (n)  x 64 k
  u16* st = (u16*)lds;     // epilogue stage: 64 rows x 264 u16 (pad 8)
  int t = threadIdx.x;
  const int gx = NP / 256;
  int orig = blockIdx.y * gx + blockIdx.x;
  const int tot = gx * 256;
  int lid = (orig & 7) * (tot >> 3) + (orig >> 3);  // XCD-chunked (tot%8==0)
  int nt = lid % gx;
  int m = lid / gx;
  int l = t & 63, w = t >> 6;
  int wm = w >> 1, wn = w & 1;  // wave tile: 64 bs x 128 n
  f32x4 acc[4][8];
#pragma unroll
  for (int a_ = 0; a_ < 4; a_++)
#pragma unroll
    for (int b_ = 0; b_ < 8; b_++) acc[a_][b_] = (f32x4){0.f, 0.f, 0.f, 0.f};
  const u16* Bb = Bm + ((size_t)m * NP + nt * 256) * 256;
  int srow = t >> 3, ss = t & 7;  // srow 0..63, ss = k-chunk
  uint4 ra[4], rb[4];
#pragma unroll
  for (int i = 0; i < 4; i++) {
    int row = i * 64 + srow;
    ra[i] = *(const uint4*)(A + ((size_t)row * 256 + m) * 256 + ss * 8);
    rb[i] = *(const uint4*)(Bb + (size_t)row * 256 + ss * 8);
  }
  for (int kt = 0; kt < 4; kt++) {
    if (kt) __syncthreads();
#pragma unroll
    for (int i = 0; i < 4; i++) {
      int row = i * 64 + srow;
      int sw = ((ss ^ (row & 7)) << 4);
      *(uint4*)(As + row * 128 + sw) = ra[i];
      *(uint4*)(Bs + row * 128 + sw) = rb[i];
    }
    if (kt < 3) {
#pragma unroll
      for (int i = 0; i < 4; i++) {
        int row = i * 64 + srow;
        ra[i] = *(const uint4*)(A + ((size_t)row * 256 + m) * 256 +
                                (kt + 1) * 64 + ss * 8);
        rb[i] =
            *(const uint4*)(Bb + (size_t)row * 256 + (kt + 1) * 64 + ss * 8);
      }
    }
    __syncthreads();
#pragma unroll
    for (int kk = 0; kk < 2; kk++) {
      short8 af[4], bg[8];
#pragma unroll
      for (int fm = 0; fm < 4; fm++) {
        int row = wm * 64 + fm * 16 + (l & 15);
        int chunk = kk * 4 + (l >> 4);
        af[fm] = *(const short8*)(As + row * 128 + ((chunk ^ (row & 7)) << 4));
      }
#pragma unroll
      for (int fn = 0; fn < 8; fn++) {
        int row = wn * 128 + fn * 16 + (l & 15);
        int chunk = kk * 4 + (l >> 4);
        bg[fn] = *(const short8*)(Bs + row * 128 + ((chunk ^ (row & 7)) << 4));
      }
#pragma unroll
      for (int fm = 0; fm < 4; fm++)
#pragma unroll
        for (int fn = 0; fn < 8; fn++)
          acc[fm][fn] = __builtin_amdgcn_mfma_f32_16x16x32_bf16(
              bg[fn], af[fm], acc[fm][fn], 0, 0, 0);  // C^T fragments
    }
  }
  // epilogue: per fm, stage 64 bs x 256 n bf16 in LDS, store 512B rows.
#pragma unroll
  for (int fm = 0; fm < 4; fm++) {
    __syncthreads();
    int rloc = wm * 16 + (l & 15);
#pragma unroll
    for (int fn = 0; fn < 8; fn++) {
      int col = wn * 128 + fn * 16 + (l >> 4) * 4;
      ushort4 u;
      u.x = f2b(acc[fm][fn][0]);
      u.y = f2b(acc[fm][fn][1]);
      u.z = f2b(acc[fm][fn][2]);
      u.w = f2b(acc[fm][fn][3]);
      *(ushort4*)(st + rloc * 264 + col) = u;
    }
    __syncthreads();
#pragma unroll
    for (int it = 0; it < 4; it++) {
      int idx = it * 512 + t;  // 0..2047
      int row = idx >> 5;      // 0..63
      int ch = idx & 31;       // 16B chunk within 512B row
      uint4 v = *(const uint4*)(st + row * 264 + ch * 8);
      int bs = (row >> 4) * 64 + fm * 16 + (row & 15);
      *(uint4*)(Cb + ((size_t)nt * 65536 + (size_t)m * 256 + bs) * 256 +
                ch * 8) = v;
    }
  }
}

// ---------------- transpose: OUTb[m][bs][2c+q] -> OUTt[bs][c][2m+q] --------
__global__ __launch_bounds__(256) void k_transp_out(
    const ushort2* __restrict__ OUTb2, ushort2* __restrict__ OUTt2) {
  __shared__ ushort2 ld[128][129];
  int t = threadIdx.x;
  int bs = blockIdx.x;
  for (int mh = 0; mh < 2; mh++) {
    if (mh) __syncthreads();
    {
      int cidx = t & 127;
      int rb = t >> 7;
      for (int pass = 0; pass < 64; pass++) {
        int r = pass * 2 + rb;
        ld[r][cidx] = OUTb2[((size_t)(mh * 128 + r) * 256 + bs) * 128 + cidx];
      }
    }
    __syncthreads();
    {
      int ml = t & 127;
      int cb = t >> 7;
      for (int pass = 0; pass < 64; pass++) {
        int c = pass * 2 + cb;
        OUTt2[((size_t)bs * 128 + c) * 256 + mh * 128 + ml] = ld[ml][c];
      }
    }
  }
}

// ---------------- irfftm: tmp[bs][p][c] bf16 = Widf @ OUTt -----------------
__global__ __launch_bounds__(512) void k_irfftm(
    const u16* __restrict__ Widf, const u16* __restrict__ OUTt,
    u16* __restrict__ tmp) {
  __shared__ char lds[49152];
  char* As = lds;          // 256 p-rows x 64k bf16, swizzled
  char* Bs = lds + 32768;  // 128 c-rows x 64k
  u16* st = (u16*)lds;     // epilogue stage [128][136] bf16 (34,816 B)
  int t = threadIdx.x;
  int ph = blockIdx.x, bs = blockIdx.y;
  int l = t & 63, w = t >> 6;
  int wm = w >> 1, wn = w & 1;  // 4(p) x 2(c) waves, 64x64 out each
  f32x4 acc[4][4];
#pragma unroll
  for (int a_ = 0; a_ < 4; a_++)
#pragma unroll
    for (int b_ = 0; b_ < 4; b_++) acc[a_][b_] = (f32x4){0.f, 0.f, 0.f, 0.f};
  const u16* Ab = Widf + (size_t)ph * 256 * 512;
  const u16* Bb = OUTt + (size_t)bs * 128 * 512;
  int srow = t >> 3, ss = t & 7;
  uint4 ra[4], rb[2];
#pragma unroll
  for (int i = 0; i < 4; i++)
    ra[i] = *(const uint4*)(Ab + (size_t)(i * 64 + srow) * 512 + ss * 8);
#pragma unroll
  for (int i = 0; i < 2; i++)
    rb[i] = *(const uint4*)(Bb + (size_t)(i * 64 + srow) * 512 + ss * 8);
  for (int kt = 0; kt < 8; kt++) {
    if (kt) __syncthreads();
#pragma unroll
    for (int i = 0; i < 4; i++) {
      int row = i * 64 + srow;
      *(uint4*)(As + row * 128 + ((ss ^ (row & 7)) << 4)) = ra[i];
    }
#pragma unroll
    for (int i = 0; i < 2; i++) {
      int row = i * 64 + srow;
      *(uint4*)(Bs + row * 128 + ((ss ^ (row & 7)) << 4)) = rb[i];
    }
    if (kt < 7) {
#pragma unroll
      for (int i = 0; i < 4; i++)
        ra[i] = *(const uint4*)(Ab + (size_t)(i * 64 + srow) * 512 +
                                (kt + 1) * 64 + ss * 8);
#pragma unroll
      for (int i = 0; i < 2; i++)
        rb[i] = *(const uint4*)(Bb + (size_t)(i * 64 + srow) * 512 +
                                (kt + 1) * 64 + ss * 8);
    }
    __syncthreads();
#pragma unroll
    for (int kk = 0; kk < 2; kk++) {
      short8 wf[4], bg[4];
#pragma unroll
      for (int fm = 0; fm < 4; fm++) {
        int row = wm * 64 + fm * 16 + (l & 15);
        int chunk = kk * 4 + (l >> 4);
        wf[fm] = *(const short8*)(As + row * 128 + ((chunk ^ (row & 7)) << 4));
      }
#pragma unroll
      for (int fn = 0; fn < 4; fn++) {
        int row = wn * 64 + fn * 16 + (l & 15);
        int chunk = kk * 4 + (l >> 4);
        bg[fn] = *(const short8*)(Bs + row * 128 + ((chunk ^ (row & 7)) << 4));
      }
#pragma unroll
      for (int fm = 0; fm < 4; fm++)
#pragma unroll
        for (int fn = 0; fn < 4; fn++)
          acc[fm][fn] = __builtin_amdgcn_mfma_f32_16x16x32_bf16(
              wf[fm], bg[fn], acc[fm][fn], 0, 0, 0);  // row=p, col=c
    }
  }
  // epilogue: two passes of 128 p-rows; stage [pl][c] bf16, 256B-row stores.
  for (int pass = 0; pass < 2; pass++) {
    __syncthreads();
    if ((wm >> 1) == pass) {
#pragma unroll
      for (int fm = 0; fm < 4; fm++)
#pragma unroll
        for (int fn = 0; fn < 4; fn++) {
          int c = wn * 64 + fn * 16 + (l & 15);
#pragma unroll
          for (int r = 0; r < 4; r++) {
            int pl = (wm & 1) * 64 + fm * 16 + (l >> 4) * 4 + r;
            st[pl * 136 + c] = f2b(acc[fm][fn][r]);
          }
        }
    }
    __syncthreads();
#pragma unroll
    for (int it = 0; it < 4; it++) {
      int idx = it * 512 + t;  // 0..2047 16B chunks
      int row = idx >> 4;      // 0..127 p-local
      int ch = idx & 15;
      uint4 v = *(const uint4*)(st + row * 136 + ch * 8);
      int p = ph * 256 + pass * 128 + row;
      *(uint4*)(tmp + ((size_t)bs * 1024 + p) * 128 + ch * 8) = v;
    }
  }
}

// ---------------- unshift: out[bs2][c][u2][v2] = b2f(tmp[bs_src][x,y][c]) --
__global__ __launch_bounds__(256) void k_unshift(
    const u16* __restrict__ tmp, float* __restrict__ out) {
  __shared__ float ld[2][32][33];
  int t = threadIdx.x;
  int cq = blockIdx.x;
  int bs2 = blockIdx.y;
  int b = bs2 >> 4, s2 = bs2 & 15;
  int qx2 = s2 >> 2, qy2 = s2 & 3;
  int r = t >> 3;  // load-side v2 row
  int y = (r < 16) ? r + 16 : r - 16;
  int qy = (r < 16) ? (qy2 + 3) & 3 : qy2;
  int cl4 = (t & 7) * 4;  // load-side c chunk
  int cs = t >> 3;        // store-side c_local
  int vh = (t & 7) * 4;   // store-side v2 base
  for (int u2 = 0; u2 < 32; u2++) {
    int cu = u2 & 1;
    int x = (u2 < 16) ? u2 + 16 : u2 - 16;
    int qx = (u2 < 16) ? (qx2 + 3) & 3 : qx2;
    {
      int bs_src = b * 16 + qx * 4 + qy;
      const u16* src =
          tmp + ((size_t)bs_src * 1024 + x * 32 + y) * 128 + cq * 32;
      ushort4 v = *(const ushort4*)(src + cl4);
      ld[cu][r][cl4 + 0] = b2f(v.x);
      ld[cu][r][cl4 + 1] = b2f(v.y);
      ld[cu][r][cl4 + 2] = b2f(v.z);
      ld[cu][r][cl4 + 3] = b2f(v.w);
    }
    __syncthreads();
    {
      float* dst =
          out + (((size_t)bs2 * 128 + cq * 32 + cs) << 10) + u2 * 32 + vh;
      float4 v = make_float4(ld[cu][vh + 0][cs], ld[cu][vh + 1][cs],
                             ld[cu][vh + 2][cs], ld[cu][vh + 3][cs]);
      *(float4*)dst = v;
    }
  }
}

// ---------------- K3: score partials over low modes ------------------------
__global__ __launch_bounds__(256) void k_scores(
    const ushort2* __restrict__ Xb2, const ushort2* __restrict__ Qb2,
    const ushort2* __restrict__ Kb2, float* __restrict__ Spart) {
  __shared__ float2 Xs[16][17], Qs[16][17], Ks[16][17];
  int t = threadIdx.x;
  int mc = blockIdx.x;
  int bh = blockIdx.y;
  int b = bh >> 3, h = bh & 7;
  int i = t >> 4, j = t & 15;
  int bs = b * 16 + i;
  int d = j;
  int m0 = mc * 32;
  size_t xoff = ((size_t)bs * 256 + m0) * 128 + h * 16 + d;
  size_t qoff = ((size_t)m0 * 256 + bs) * 128 + h * 16 + d;
  ushort2 ux = Xb2[xoff];
  ushort2 uq = Qb2[qoff];
  ushort2 uk = Kb2[qoff];
  float acc = 0.f;
  for (int mm = 0; mm < 32; mm++) {
    int m = m0 + mm;
    Xs[i][d] = make_float2(b2f(ux.x), b2f(ux.y));
    Qs[i][d] = make_float2(b2f(uq.x), b2f(uq.y));
    Ks[i][d] = make_float2(b2f(uk.x), b2f(uk.y));
    __syncthreads();
    if (mm < 31) {
      ux = Xb2[xoff + (size_t)(mm + 1) * 128];
      uq = Qb2[qoff + (size_t)(mm + 1) * 32768];
      uk = Kb2[qoff + (size_t)(mm + 1) * 32768];
    }
    int ky = m & 15, kx = m >> 4;
    if (ky > 0) {
#pragma unroll
      for (int dd = 0; dd < 16; dd++) {
        float2 Xi = Xs[i][dd], Qi = Qs[i][dd], Xj = Xs[j][dd], Kj = Ks[j][dd];
        float qr = Xi.x + Qi.x, qi = Xi.y + Qi.y;
        float kr = Xj.x + Kj.x, ki = Xj.y + Kj.y;
        acc += 2.f * (qr * kr + qi * ki - (Xi.x * Xj.x + Xi.y * Xj.y));
      }
    } else {
#pragma unroll
      for (int dd = 0; dd < 16; dd++) {
        float2 Xi = Xs[i][dd], Qi = Qs[i][dd], Xj = Xs[j][dd], Kj = Ks[j][dd];
        float cr = Xi.x * Kj.x + Xi.y * Kj.y + Qi.x * Xj.x + Qi.y * Xj.y;
        float qk =
            (kx == 0) ? (Qi.x * Kj.x) : 0.5f * (Qi.x * Kj.x + Qi.y * Kj.y);
        acc += cr + qk;
      }
    }
    __syncthreads();
  }
  Spart[((size_t)mc * 128 + bh) * 256 + t] = acc;
}

// ---------------- K3b: assemble scores, bias, softmax ----------------------
__global__ __launch_bounds__(256) void k_softmax(
    const float* __restrict__ Spart, const float* __restrict__ Gfull,
    const float* __restrict__ biasb, float* __restrict__ attn) {
  int t = threadIdx.x;
  int bh = blockIdx.x;
  int b = bh >> 3, h = bh & 7;
  int i = t >> 4, j = t & 15;
  float acc = 0.f;
#pragma unroll
  for (int mc = 0; mc < 8; mc++)
    acc += Spart[((size_t)mc * 128 + bh) * 256 + t];
  float G = Gfull[(size_t)bh * 256 + t];
  float score = G * (1.f / 4096.f) + acc * (1.f / 4194304.f) +
                biasb[(((b & 3) * 8 + h) * 16 + i) * 16 + j];
  float mx = score;
#pragma unroll
  for (int o = 8; o >= 1; o >>= 1) mx = fmaxf(mx, __shfl_xor(mx, o, 16));
  float e = expf(score - mx);
  float sm = e;
#pragma unroll
  for (int o = 8; o >= 1; o >>= 1) sm += __shfl_xor(sm, o, 16);
  attn[(size_t)bh * 256 + t] = e / sm;
}

// ---------------- K4: SAf[bs][m][c] = attn @ (X + Vm~)  (bf16 out) ---------
__global__ __launch_bounds__(256) void k_sav(
    const ushort2* __restrict__ Xb2, const ushort2* __restrict__ Vb2,
    const float* __restrict__ attn, ushort2* __restrict__ SAfb) {
  __shared__ float at[8][16][17];
  __shared__ float2 vt[16][130];
  int t = threadIdx.x;
  int mc = blockIdx.x;
  int b = blockIdx.y;
  {
    int h = t >> 5, ii = (t >> 1) & 15, jb = (t & 1) * 8;
#pragma unroll
    for (int k = 0; k < 8; k++)
      at[h][ii][jb + k] = attn[((size_t)(b * 8 + h) * 16 + ii) * 16 + jb + k];
  }
  __syncthreads();
  int i = t >> 4, cg = t & 15;
  for (int mm = 0; mm < 16; mm++) {
    int m = mc * 16 + mm;
    int ky = m & 15, kx = m >> 4;
    {
      int jj = t >> 4;
      size_t vrow = ((size_t)m * 256 + b * 16 + jj) * 128;
      size_t xrow = ((size_t)(b * 16 + jj) * 256 + m) * 128;
#pragma unroll
      for (int u = 0; u < 8; u++) {
        int c = cg + u * 16;
        ushort2 uv = Vb2[vrow + c];
        float2 vm = make_float2(b2f(uv.x), b2f(uv.y));
        ushort2 uxv = Xb2[xrow + c];
        float2 xv = make_float2(b2f(uxv.x), b2f(uxv.y));
        float2 vh;
        if (ky == 0) {
          if (kx == 0)
            vh = make_float2(xv.x + vm.x, xv.y);
          else
            vh = make_float2(xv.x + 0.5f * vm.x, xv.y + 0.5f * vm.y);
        } else
          vh = make_float2(xv.x + vm.x, xv.y + vm.y);
        vt[jj][c] = vh;
      }
    }
    __syncthreads();
    float2 o8[8];
#pragma unroll
    for (int u = 0; u < 8; u++) o8[u] = make_float2(0.f, 0.f);
#pragma unroll
    for (int jj = 0; jj < 16; jj++) {
#pragma unroll
      for (int u = 0; u < 8; u++) {
        float av = at[u][i][jj];
        float2 v = vt[jj][cg + u * 16];
        o8[u].x += av * v.x;
        o8[u].y += av * v.y;
      }
    }
    size_t orow = ((size_t)(b * 16 + i) * 256 + m) * 128;  // [bs][m][128]
#pragma unroll
    for (int u = 0; u < 8; u++) {
      ushort2 ub;
      ub.x = f2b(o8[u].x);
      ub.y = f2b(o8[u].y);
      SAfb[orow + cg + u * 16] = ub;
    }
    __syncthreads();
  }
}

// ---------------------------------------------------------------------------
extern "C" void kernel_launch(void* const* d_in, const int* in_sizes, int n_in,
                              void* d_out, int out_size, void* d_ws,
                              size_t ws_size, hipStream_t stream) {
  (void)in_sizes;
  (void)n_in;
  const float* seq = (const float*)d_in[0];
  const float* qwr = (const float*)d_in[1];
  const float* qwi = (const float*)d_in[2];
  const float* owr = (const float*)d_in[3];
  const float* owi = (const float*)d_in[4];
  const float* cw1 = (const float*)d_in[5];
  const float* cb1 = (const float*)d_in[6];
  const float* cw2 = (const float*)d_in[7];
  const float* amask = (const float*)d_in[8];
  float* out = (float*)d_out;
  char* ws = (char*)d_ws;

  const size_t R = 100663296;  // 96 MiB region
  // R1: Wq_s1b (50.3MB); Xbf at +64MB; Wob aliases ws after build_b<384>
  ushort2* Wq_s1b = (ushort2*)ws;
  u16* Xbf = (u16*)(ws + 67108864);  // [bs][m][256]
  ushort2* Xb2 = (ushort2*)Xbf;
  u16* Wob = (u16*)ws;
  // R2: QKV [3][m][bs][256] (100.6MB) -> after sav: OUTb + OUTt
  u16* QKV = (u16*)(ws + R);
  ushort2* Qb2 = (ushort2*)QKV;
  ushort2* Kb2 = Qb2 + 8388608;
  ushort2* Vb2 = Qb2 + 16777216;
  u16* OUTb = (u16*)(ws + R);
  u16* OUTt = (u16*)(ws + R + 33554432);
  // tmp bf16 [bs][p][c] = 64 MiB at [160 MiB, 224 MiB)
  u16* tmpb = (u16*)(ws + R + 2 * 33554432);
  // R3: Wqb (100.6MB) -> SAfb (33.5MB) after mix1
  u16* Wqb = (u16*)(ws + 2 * R);
  ushort2* SAfb = (ushort2*)(ws + 2 * R);
  // R4: Wo_s1b bf16 (16.8MB)
  ushort2* Wo_s1b = (ushort2*)(ws + 3 * R);
  char* sm = ws + 3 * R + 16777216 + 67108864;
  u16* Wdft = (u16*)sm;                   // 1,048,576
  float* Gfull = (float*)(sm + 1048576);  // 131,072 (slot 524,288)
  float* biasb = (float*)(sm + 1572864);  // 32,768
  float* attn = (float*)(sm + 1605632);   // 131,072
  float* Spart = (float*)(sm + 1736704);  // 1,048,576
  u16* Widf = (u16*)(sm + 2785280);       // 1,048,576
  size_t need = 3 * R + 16777216 + 67108864 + 2785280 + 1048576;

  if (ws_size < need) {
    hipMemsetAsync(d_out, 0, (size_t)out_size * 4, stream);
    return;
  }

  dim3 blk(256);
  k_transpose_wb<<<dim3(24, 16), blk, 0, stream>>>(qwr, qwi, Wq_s1b, 384);
  k_build_b<384><<<dim3(6, 256), blk, 0, stream>>>(Wq_s1b, Wqb);
  k_transpose_wb<<<dim3(8, 16), blk, 0, stream>>>(owr, owi, Wo_s1b, 128);
  k_bias<<<dim3(1), blk, 0, stream>>>(cw1, cb1, cw2, amask, biasb);
  k_build_wdft<<<dim3(512), blk, 0, stream>>>(Wdft);
  k_build_widft<<<dim3(1024), blk, 0, stream>>>(Widf);
  k_dftm<<<dim3(2, 256), dim3(512), 0, stream>>>(Wdft, seq, Xbf);
  k_gram_seq<<<dim3(128), blk, 0, stream>>>(seq, Gfull);
  k_mixm<768><<<dim3(3, 256), dim3(512), 0, stream>>>(Xbf, Wqb, QKV);
  k_scores<<<dim3(8, 128), blk, 0, stream>>>(Xb2, Qb2, Kb2, Spart);
  k_softmax<<<dim3(128), blk, 0, stream>>>(Spart, Gfull, biasb, attn);
  k_build_b<128><<<dim3(2, 256), blk, 0, stream>>>(Wo_s1b, Wob);
  k_sav<<<dim3(16, 16), blk, 0, stream>>>(Xb2, Vb2, attn, SAfb);
  k_mixm<256><<<dim3(1, 256), dim3(512), 0, stream>>>((const u16*)SAfb, Wob,
                                                      OUTb);
  k_transp_out<<<dim3(256), blk, 0, stream>>>((const ushort2*)OUTb,
                                              (ushort2*)OUTt);
  k_irfftm<<<dim3(4, 256), dim3(512), 0, stream>>>(Widf, OUTt, tmpb);
  k_unshift<<<dim3(4, 256), blk, 0, stream>>>(tmpb, out);
}